// Round 1
// baseline (914.009 us; speedup 1.0000x reference)
//
#include <hip/hip_runtime.h>
#include <math.h>

#define NN 20000
#define EE 640000
// H=8, Ch=Kh=16, C=K=128, EC=64

__device__ __forceinline__ float ssp(float x) {
    // softplus(x) - ln(2)
    float sp;
    if (x > 20.f)       sp = x;
    else if (x < -20.f) sp = __expf(x);
    else                sp = log1pf(__expf(x));
    return sp - 0.69314718055994530942f;
}

// ---------------- per-node precompute: h_k, h_v, q~ (wkl^T hq * 0.25), qb, cen ----------------
__global__ __launch_bounds__(128) void node_pre(
    const float* __restrict__ node_attr,
    const float* __restrict__ k_w, const float* __restrict__ q_w, const float* __restrict__ v_w,
    const float* __restrict__ wkl_w, const float* __restrict__ wkl_b,
    const float* __restrict__ cen_w, const float* __restrict__ cen_b,
    float* __restrict__ hk_g, float* __restrict__ hv_g,
    float* __restrict__ qt_g, float* __restrict__ qb_g, float* __restrict__ cen_g)
{
    const int n = blockIdx.x;
    const int t = threadIdx.x;
    __shared__ float x[128];
    __shared__ float hq[128];
    x[t] = node_attr[(size_t)n * 128 + t];
    __syncthreads();
    const int h = t >> 4, i = t & 15;
    const float* xh = &x[h * 16];
    const float* kw = &k_w[h * 256 + i * 16];
    const float* qw = &q_w[h * 256 + i * 16];
    const float* vw = &v_w[h * 256 + i * 16];
    float accK = 0.f, accQ = 0.f, accV = 0.f;
#pragma unroll
    for (int j = 0; j < 16; j++) {
        float xv = xh[j];
        accK = fmaf(xv, kw[j], accK);
        accQ = fmaf(xv, qw[j], accQ);
        accV = fmaf(xv, vw[j], accV);
    }
    hk_g[(size_t)n * 128 + t] = accK;
    hv_g[(size_t)n * 128 + t] = accV;
    hq[t] = accQ;
    __syncthreads();
    // qt[n,h,i] = 0.25 * sum_o hq[h,o] * wkl_w[o,i]
    float qt = 0.f;
#pragma unroll
    for (int o = 0; o < 16; o++) qt = fmaf(hq[h * 16 + o], wkl_w[o * 16 + i], qt);
    qt_g[(size_t)n * 128 + t] = 0.25f * qt;
    if (i == 0) {
        float qb = 0.f;
#pragma unroll
        for (int o = 0; o < 16; o++) qb = fmaf(hq[h * 16 + o], wkl_b[o], qb);
        qb_g[(size_t)n * 8 + h] = 0.25f * qb;
    }
    // cen[n,t] = node_attr[n,:] . cen_w[t,:] + cen_b[t]
    float acc = cen_b[t];
    const float* cw = &cen_w[(size_t)t * 128];
#pragma unroll 8
    for (int c = 0; c < 128; c++) acc = fmaf(x[c], cw[c], acc);
    cen_g[(size_t)n * 128 + t] = acc;
}

// ---------------- CSR build ----------------
__global__ void count_kernel(const int* __restrict__ ei, int* __restrict__ cnt) {
    int e = blockIdx.x * 256 + threadIdx.x;
    if (e < EE) atomicAdd(&cnt[ei[e]], 1);
}

__global__ __launch_bounds__(1024) void scan_kernel(const int* __restrict__ cnt,
                                                    int* __restrict__ off, int* __restrict__ cursor) {
    __shared__ int arr[1024];
    const int t = threadIdx.x;
    const int STRIP = 20; // 1024*20 >= 20000
    int start = t * STRIP;
    int end = start + STRIP; if (end > NN) end = NN;
    int local = 0;
    for (int n = start; n < end; n++) local += cnt[n];
    arr[t] = local;
    __syncthreads();
    for (int s = 1; s < 1024; s <<= 1) {
        int v = (t >= s) ? arr[t - s] : 0;
        __syncthreads();
        arr[t] += v;
        __syncthreads();
    }
    int running = arr[t] - local; // exclusive prefix
    for (int n = start; n < end; n++) {
        off[n] = running;
        cursor[n] = running;
        running += cnt[n];
    }
    if (end == NN) off[NN] = running;
}

__global__ void scatter_kernel(const int* __restrict__ ei, int* __restrict__ cursor,
                               int* __restrict__ csr) {
    int e = blockIdx.x * 256 + threadIdx.x;
    if (e < EE) {
        int p = atomicAdd(&cursor[ei[e]], 1);
        csr[p] = e;
    }
}

// ---------------- per-edge pass: W_v, ex = exp(qk) ----------------
__global__ __launch_bounds__(256) void edge_pass(
    const float* __restrict__ edge_attr, const int* __restrict__ ei,
    const float* __restrict__ wk1_w, const float* __restrict__ wk1_b,
    const float* __restrict__ wk2_w, const float* __restrict__ wk2_b,
    const float* __restrict__ wv1_w, const float* __restrict__ wv1_b,
    const float* __restrict__ wv2_w, const float* __restrict__ wv2_b,
    const float* __restrict__ hk_g, const float* __restrict__ qt_g, const float* __restrict__ qb_g,
    float* __restrict__ Wv_g, float* __restrict__ ex_g)
{
    const int e = blockIdx.x * 256 + threadIdx.x;
    const int r = ei[e];
    const int c = ei[EE + e];

    float tk[16], tv[16];
#pragma unroll
    for (int i = 0; i < 16; i++) { tk[i] = wk1_b[i]; tv[i] = wv1_b[i]; }

    const float4* ea4 = (const float4*)(edge_attr + (size_t)e * 64);
#pragma unroll
    for (int j4 = 0; j4 < 16; j4++) {
        float4 a = ea4[j4];
#pragma unroll
        for (int i = 0; i < 16; i++) {
            const float* wk = wk1_w + i * 64 + j4 * 4;
            const float* wv = wv1_w + i * 64 + j4 * 4;
            tk[i] = fmaf(a.x, wk[0], tk[i]);
            tk[i] = fmaf(a.y, wk[1], tk[i]);
            tk[i] = fmaf(a.z, wk[2], tk[i]);
            tk[i] = fmaf(a.w, wk[3], tk[i]);
            tv[i] = fmaf(a.x, wv[0], tv[i]);
            tv[i] = fmaf(a.y, wv[1], tv[i]);
            tv[i] = fmaf(a.z, wv[2], tv[i]);
            tv[i] = fmaf(a.w, wv[3], tv[i]);
        }
    }
#pragma unroll
    for (int i = 0; i < 16; i++) { tk[i] = ssp(tk[i]); tv[i] = ssp(tv[i]); }

    float Wk[16], Wv[16];
#pragma unroll
    for (int i = 0; i < 16; i++) {
        float ak = wk2_b[i], av = wv2_b[i];
#pragma unroll
        for (int j = 0; j < 16; j++) {
            ak = fmaf(tk[j], wk2_w[i * 16 + j], ak);
            av = fmaf(tv[j], wv2_w[i * 16 + j], av);
        }
        Wk[i] = ak; Wv[i] = av;
    }

    float4* wvo = (float4*)(Wv_g + (size_t)e * 16);
    wvo[0] = make_float4(Wv[0], Wv[1], Wv[2], Wv[3]);
    wvo[1] = make_float4(Wv[4], Wv[5], Wv[6], Wv[7]);
    wvo[2] = make_float4(Wv[8], Wv[9], Wv[10], Wv[11]);
    wvo[3] = make_float4(Wv[12], Wv[13], Wv[14], Wv[15]);

    float qb[8];
    {
        const float4* qb4 = (const float4*)(qb_g + (size_t)r * 8);
        float4 a = qb4[0], b = qb4[1];
        qb[0] = a.x; qb[1] = a.y; qb[2] = a.z; qb[3] = a.w;
        qb[4] = b.x; qb[5] = b.y; qb[6] = b.z; qb[7] = b.w;
    }
    const float4* hk4 = (const float4*)(hk_g + (size_t)c * 128);
    const float4* qt4 = (const float4*)(qt_g + (size_t)r * 128);
    float exv[8];
#pragma unroll
    for (int h = 0; h < 8; h++) {
        float s = qb[h];
#pragma unroll
        for (int q = 0; q < 4; q++) {
            float4 hk = hk4[h * 4 + q];
            float4 qt = qt4[h * 4 + q];
            s = fmaf(Wk[q * 4 + 0] * hk.x, qt.x, s);
            s = fmaf(Wk[q * 4 + 1] * hk.y, qt.y, s);
            s = fmaf(Wk[q * 4 + 2] * hk.z, qt.z, s);
            s = fmaf(Wk[q * 4 + 3] * hk.w, qt.w, s);
        }
        exv[h] = __expf(s);
    }
    float4* exo = (float4*)(ex_g + (size_t)e * 8);
    exo[0] = make_float4(exv[0], exv[1], exv[2], exv[3]);
    exo[1] = make_float4(exv[4], exv[5], exv[6], exv[7]);
}

// ---------------- per-node aggregation + output MLP + LayerNorm ----------------
__global__ __launch_bounds__(128) void node_aggr(
    const int* __restrict__ ei,
    const int* __restrict__ off, const int* __restrict__ csr,
    const float* __restrict__ ex_g, const float* __restrict__ Wv_g,
    const float* __restrict__ hv_g,
    const float* __restrict__ wvl_w, const float* __restrict__ wvl_b,
    const float* __restrict__ cen_g,
    const float* __restrict__ out_w, const float* __restrict__ out_b,
    const float* __restrict__ ln_g, const float* __restrict__ ln_b,
    float* __restrict__ out)
{
    const int n = blockIdx.x, t = threadIdx.x;
    const int h = t >> 4, i = t & 15;
    const int base = off[n];
    const int cnt = off[n + 1] - base;

    // denominator for this head (redundant across the 16 i-threads; broadcast loads)
    float d = 0.f;
    for (int j = 0; j < cnt; j++) {
        int e = csr[base + j];
        d += ex_g[(size_t)e * 8 + h];
    }
    float rd = (cnt > 0) ? (1.f / d) : 0.f;

    float S = 0.f;
    for (int j = 0; j < cnt; j++) {
        int e = csr[base + j];
        int c = ei[EE + e];
        float a = ex_g[(size_t)e * 8 + h] * rd;
        S += a * Wv_g[(size_t)e * 16 + i] * hv_g[(size_t)c * 128 + t];
    }

    __shared__ float sl[128];
    __shared__ float vl[128];
    sl[t] = S;
    __syncthreads();
    // aggr[h, o=i] = sum_j wvl_w[o,j] * S[h,j] + (cnt>0) * wvl_b[o]
    float agg = (cnt > 0) ? wvl_b[i] : 0.f;
#pragma unroll
    for (int j = 0; j < 16; j++) agg = fmaf(wvl_w[i * 16 + j], sl[h * 16 + j], agg);

    float pre = cen_g[(size_t)n * 128 + t] + agg;
    vl[t] = ssp(pre);
    __syncthreads();

    float acc = out_b[t];
    const float* ow = &out_w[(size_t)t * 128];
#pragma unroll 8
    for (int c = 0; c < 128; c++) acc = fmaf(vl[c], ow[c], acc);

    // LayerNorm over the 128 channels (one per thread)
    __shared__ float red[128];
    red[t] = acc;
    __syncthreads();
    for (int s = 64; s > 0; s >>= 1) { if (t < s) red[t] += red[t + s]; __syncthreads(); }
    float mean = red[0] * (1.f / 128.f);
    __syncthreads();
    red[t] = acc * acc;
    __syncthreads();
    for (int s = 64; s > 0; s >>= 1) { if (t < s) red[t] += red[t + s]; __syncthreads(); }
    float var = red[0] * (1.f / 128.f) - mean * mean;
    float inv = rsqrtf(var + 1e-5f);
    out[(size_t)n * 128 + t] = (acc - mean) * inv * ln_g[t] + ln_b[t];
}

extern "C" void kernel_launch(void* const* d_in, const int* in_sizes, int n_in,
                              void* d_out, int out_size, void* d_ws, size_t ws_size,
                              hipStream_t stream)
{
    (void)in_sizes; (void)n_in; (void)out_size; (void)ws_size;
    const float* node_attr = (const float*)d_in[0];
    const int*   edge_index= (const int*)d_in[1];
    const float* edge_attr = (const float*)d_in[2];
    const float* k_w  = (const float*)d_in[3];
    const float* q_w  = (const float*)d_in[4];
    const float* v_w  = (const float*)d_in[5];
    const float* wk1_w= (const float*)d_in[6];  const float* wk1_b= (const float*)d_in[7];
    const float* wk2_w= (const float*)d_in[8];  const float* wk2_b= (const float*)d_in[9];
    const float* wkl_w= (const float*)d_in[10]; const float* wkl_b= (const float*)d_in[11];
    const float* wv1_w= (const float*)d_in[12]; const float* wv1_b= (const float*)d_in[13];
    const float* wv2_w= (const float*)d_in[14]; const float* wv2_b= (const float*)d_in[15];
    const float* wvl_w= (const float*)d_in[16]; const float* wvl_b= (const float*)d_in[17];
    const float* cen_w= (const float*)d_in[18]; const float* cen_b= (const float*)d_in[19];
    const float* out_w= (const float*)d_in[20]; const float* out_b= (const float*)d_in[21];
    const float* ln_g = (const float*)d_in[22]; const float* ln_b = (const float*)d_in[23];
    float* out = (float*)d_out;

    char* ws = (char*)d_ws;
    size_t o = 0;
    auto alloc = [&](size_t bytes) -> void* {
        void* p = ws + o;
        o += (bytes + 255) & ~(size_t)255;
        return p;
    };
    float* hk_g  = (float*)alloc((size_t)NN * 128 * 4);
    float* hv_g  = (float*)alloc((size_t)NN * 128 * 4);
    float* qt_g  = (float*)alloc((size_t)NN * 128 * 4);
    float* cen_g = (float*)alloc((size_t)NN * 128 * 4);
    float* qb_g  = (float*)alloc((size_t)NN * 8 * 4);
    float* Wv_g  = (float*)alloc((size_t)EE * 16 * 4);
    float* ex_g  = (float*)alloc((size_t)EE * 8 * 4);
    int* cnt     = (int*)alloc((size_t)NN * 4);
    int* off     = (int*)alloc((size_t)(NN + 1) * 4);
    int* cursor  = (int*)alloc((size_t)NN * 4);
    int* csr     = (int*)alloc((size_t)EE * 4);

    hipMemsetAsync(cnt, 0, (size_t)NN * 4, stream);

    node_pre<<<NN, 128, 0, stream>>>(node_attr, k_w, q_w, v_w, wkl_w, wkl_b,
                                     cen_w, cen_b, hk_g, hv_g, qt_g, qb_g, cen_g);
    count_kernel<<<(EE + 255) / 256, 256, 0, stream>>>(edge_index, cnt);
    scan_kernel<<<1, 1024, 0, stream>>>(cnt, off, cursor);
    scatter_kernel<<<(EE + 255) / 256, 256, 0, stream>>>(edge_index, cursor, csr);
    edge_pass<<<EE / 256, 256, 0, stream>>>(edge_attr, edge_index,
                                            wk1_w, wk1_b, wk2_w, wk2_b,
                                            wv1_w, wv1_b, wv2_w, wv2_b,
                                            hk_g, qt_g, qb_g, Wv_g, ex_g);
    node_aggr<<<NN, 128, 0, stream>>>(edge_index, off, csr, ex_g, Wv_g, hv_g,
                                      wvl_w, wvl_b, cen_g, out_w, out_b,
                                      ln_g, ln_b, out);
}

// Round 2
// 735.271 us; speedup vs baseline: 1.2431x; 1.2431x over previous
//
#include <hip/hip_runtime.h>
#include <math.h>

#define NN 20000
#define EE 640000
// H=8, Ch=Kh=16, C=K=128, EC=64

typedef __attribute__((ext_vector_type(8))) short short8;
typedef __attribute__((ext_vector_type(4))) float f32x4;

__device__ __forceinline__ float ssp(float x) {
    // softplus(x) - ln(2)
    float sp;
    if (x > 20.f)       sp = x;
    else if (x < -20.f) sp = __expf(x);
    else                sp = log1pf(__expf(x));
    return sp - 0.69314718055994530942f;
}

__device__ __forceinline__ short f2bf(float f) {
    // f32 -> bf16 round-to-nearest-even
    unsigned u = __float_as_uint(f);
    unsigned r = (u + 0x7FFFu + ((u >> 16) & 1u)) >> 16;
    return (short)r;
}

__device__ __forceinline__ float4 ld4(const float* p) { return *(const float4*)p; }

__device__ __forceinline__ short8 pack8(float4 p, float4 q) {
    short8 r;
    r[0] = f2bf(p.x); r[1] = f2bf(p.y); r[2] = f2bf(p.z); r[3] = f2bf(p.w);
    r[4] = f2bf(q.x); r[5] = f2bf(q.y); r[6] = f2bf(q.z); r[7] = f2bf(q.w);
    return r;
}

// ---------------- per-node precompute: h_k, h_v, q~ (wkl^T hq * 0.25), qb, cen ----------------
__global__ __launch_bounds__(128) void node_pre(
    const float* __restrict__ node_attr,
    const float* __restrict__ k_w, const float* __restrict__ q_w, const float* __restrict__ v_w,
    const float* __restrict__ wkl_w, const float* __restrict__ wkl_b,
    const float* __restrict__ cen_w, const float* __restrict__ cen_b,
    float* __restrict__ hk_g, float* __restrict__ hv_g,
    float* __restrict__ qt_g, float* __restrict__ qb_g, float* __restrict__ cen_g)
{
    const int n = blockIdx.x;
    const int t = threadIdx.x;
    __shared__ float x[128];
    __shared__ float hq[128];
    x[t] = node_attr[(size_t)n * 128 + t];
    __syncthreads();
    const int h = t >> 4, i = t & 15;
    const float* xh = &x[h * 16];
    const float* kw = &k_w[h * 256 + i * 16];
    const float* qw = &q_w[h * 256 + i * 16];
    const float* vw = &v_w[h * 256 + i * 16];
    float accK = 0.f, accQ = 0.f, accV = 0.f;
#pragma unroll
    for (int j = 0; j < 16; j++) {
        float xv = xh[j];
        accK = fmaf(xv, kw[j], accK);
        accQ = fmaf(xv, qw[j], accQ);
        accV = fmaf(xv, vw[j], accV);
    }
    hk_g[(size_t)n * 128 + t] = accK;
    hv_g[(size_t)n * 128 + t] = accV;
    hq[t] = accQ;
    __syncthreads();
    float qt = 0.f;
#pragma unroll
    for (int o = 0; o < 16; o++) qt = fmaf(hq[h * 16 + o], wkl_w[o * 16 + i], qt);
    qt_g[(size_t)n * 128 + t] = 0.25f * qt;
    if (i == 0) {
        float qb = 0.f;
#pragma unroll
        for (int o = 0; o < 16; o++) qb = fmaf(hq[h * 16 + o], wkl_b[o], qb);
        qb_g[(size_t)n * 8 + h] = 0.25f * qb;
    }
    float acc = cen_b[t];
    const float* cw = &cen_w[(size_t)t * 128];
#pragma unroll 8
    for (int c = 0; c < 128; c++) acc = fmaf(x[c], cw[c], acc);
    cen_g[(size_t)n * 128 + t] = acc;
}

// ---------------- CSR build ----------------
__global__ void count_kernel(const int* __restrict__ ei, int* __restrict__ cnt) {
    int e = blockIdx.x * 256 + threadIdx.x;
    if (e < EE) atomicAdd(&cnt[ei[e]], 1);
}

__global__ __launch_bounds__(1024) void scan_kernel(const int* __restrict__ cnt,
                                                    int* __restrict__ off, int* __restrict__ cursor) {
    __shared__ int arr[1024];
    const int t = threadIdx.x;
    const int STRIP = 20;
    int start = t * STRIP;
    int end = start + STRIP; if (end > NN) end = NN;
    int local = 0;
    for (int n = start; n < end; n++) local += cnt[n];
    arr[t] = local;
    __syncthreads();
    for (int s = 1; s < 1024; s <<= 1) {
        int v = (t >= s) ? arr[t - s] : 0;
        __syncthreads();
        arr[t] += v;
        __syncthreads();
    }
    int running = arr[t] - local;
    for (int n = start; n < end; n++) {
        off[n] = running;
        cursor[n] = running;
        running += cnt[n];
    }
    if (end == NN) off[NN] = running;
}

__global__ void scatter_kernel(const int* __restrict__ ei, int* __restrict__ cursor,
                               int* __restrict__ csr) {
    int e = blockIdx.x * 256 + threadIdx.x;
    if (e < EE) {
        int p = atomicAdd(&cursor[ei[e]], 1);
        csr[p] = e;
    }
}

// ---------------- fused edge pass: MFMA MLPs + qk/exp ----------------
// Block = 256 threads = 4 waves; each wave runs the MLPs for 16 edges via
// mfma_f32_16x16x32_bf16; phase 2 remaps 4 threads/edge for qk gathers.
__global__ __launch_bounds__(256) void edge_fused(
    const float* __restrict__ edge_attr, const int* __restrict__ ei,
    const float* __restrict__ wk1_w, const float* __restrict__ wk1_b,
    const float* __restrict__ wk2_w, const float* __restrict__ wk2_b,
    const float* __restrict__ wv1_w, const float* __restrict__ wv1_b,
    const float* __restrict__ wv2_w, const float* __restrict__ wv2_b,
    const float* __restrict__ hk_g, const float* __restrict__ qt_g, const float* __restrict__ qb_g,
    float* __restrict__ Wv_g, float* __restrict__ ex_g)
{
    __shared__ __align__(16) short lds_k[4][16][16];  // ssp(layer1_k) bf16, per-wave tile
    __shared__ __align__(16) short lds_v[4][16][16];
    __shared__ __align__(16) float lds_Wk[64][16];

    const int t = threadIdx.x;
    const int wid = t >> 6, lane = t & 63;
    const int row = lane & 15;       // A-row (edge within wave tile) / B-col (out channel)
    const int kg  = lane >> 4;       // k-group 0..3
    const int e0  = blockIdx.x * 64 + wid * 16;

    // ---- A fragments from edge_attr (shared by K and V paths) ----
    const float* ea = edge_attr + (size_t)(e0 + row) * 64 + kg * 8;
    short8 A0 = pack8(ld4(ea),      ld4(ea + 4));    // k = 0..31
    short8 A1 = pack8(ld4(ea + 32), ld4(ea + 36));   // k = 32..63

    // ---- B fragments: layer-1 weights, B[k][col] = w1[col*64 + k] ----
    const float* wkp = wk1_w + row * 64 + kg * 8;
    const float* wvp = wv1_w + row * 64 + kg * 8;
    short8 BK0 = pack8(ld4(wkp),      ld4(wkp + 4));
    short8 BK1 = pack8(ld4(wkp + 32), ld4(wkp + 36));
    short8 BV0 = pack8(ld4(wvp),      ld4(wvp + 4));
    short8 BV1 = pack8(ld4(wvp + 32), ld4(wvp + 36));

    float bk = wk1_b[row], bv = wv1_b[row];
    f32x4 ck = {bk, bk, bk, bk};
    f32x4 cv = {bv, bv, bv, bv};
    ck = __builtin_amdgcn_mfma_f32_16x16x32_bf16(A0, BK0, ck, 0, 0, 0);
    ck = __builtin_amdgcn_mfma_f32_16x16x32_bf16(A1, BK1, ck, 0, 0, 0);
    cv = __builtin_amdgcn_mfma_f32_16x16x32_bf16(A0, BV0, cv, 0, 0, 0);
    cv = __builtin_amdgcn_mfma_f32_16x16x32_bf16(A1, BV1, cv, 0, 0, 0);

    // D layout: lane holds D[row=(kg*4+r)][col=row]; apply ssp, stash bf16 in LDS
#pragma unroll
    for (int r = 0; r < 4; r++) {
        lds_k[wid][kg * 4 + r][row] = f2bf(ssp(ck[r]));
        lds_v[wid][kg * 4 + r][row] = f2bf(ssp(cv[r]));
    }
    __syncthreads();

    // ---- layer 2: K=16 zero-padded to 32 ----
    short8 A2K = (short8)0, A2V = (short8)0, B2K = (short8)0, B2V = (short8)0;
    if (kg < 2) {
        A2K = *(const short8*)&lds_k[wid][row][kg * 8];
        A2V = *(const short8*)&lds_v[wid][row][kg * 8];
        const float* w2k = wk2_w + row * 16 + kg * 8;
        const float* w2v = wv2_w + row * 16 + kg * 8;
        B2K = pack8(ld4(w2k), ld4(w2k + 4));
        B2V = pack8(ld4(w2v), ld4(w2v + 4));
    }
    float b2k = wk2_b[row], b2v = wv2_b[row];
    f32x4 c2k = {b2k, b2k, b2k, b2k};
    f32x4 c2v = {b2v, b2v, b2v, b2v};
    c2k = __builtin_amdgcn_mfma_f32_16x16x32_bf16(A2K, B2K, c2k, 0, 0, 0);
    c2v = __builtin_amdgcn_mfma_f32_16x16x32_bf16(A2V, B2V, c2v, 0, 0, 0);

    // Wv -> global (needed by node_aggr); Wk -> LDS (consumed by phase 2)
#pragma unroll
    for (int r = 0; r < 4; r++) {
        int el = kg * 4 + r;
        Wv_g[(size_t)(e0 + el) * 16 + row] = c2v[r];
        lds_Wk[wid * 16 + el][row] = c2k[r];
    }
    __syncthreads();

    // ---- phase 2: qk + exp; 4 threads per edge, 2 heads each ----
    const int e_loc = t >> 2;
    const int hp = t & 3;
    const int e = blockIdx.x * 64 + e_loc;
    const int rw = ei[e], cl = ei[EE + e];

    float wk[16];
#pragma unroll
    for (int i = 0; i < 16; i += 4) {
        float4 w = *(const float4*)&lds_Wk[e_loc][i];
        wk[i] = w.x; wk[i + 1] = w.y; wk[i + 2] = w.z; wk[i + 3] = w.w;
    }
    float2 qb = *(const float2*)(qb_g + (size_t)rw * 8 + hp * 2);
    float exv[2];
#pragma unroll
    for (int u = 0; u < 2; u++) {
        int h = hp * 2 + u;
        const float4* hk4 = (const float4*)(hk_g + (size_t)cl * 128 + h * 16);
        const float4* qt4 = (const float4*)(qt_g + (size_t)rw * 128 + h * 16);
        float s = u ? qb.y : qb.x;
#pragma unroll
        for (int q = 0; q < 4; q++) {
            float4 hk = hk4[q];
            float4 qt = qt4[q];
            s = fmaf(wk[q * 4 + 0] * hk.x, qt.x, s);
            s = fmaf(wk[q * 4 + 1] * hk.y, qt.y, s);
            s = fmaf(wk[q * 4 + 2] * hk.z, qt.z, s);
            s = fmaf(wk[q * 4 + 3] * hk.w, qt.w, s);
        }
        exv[u] = __expf(s);
    }
    *(float2*)(ex_g + (size_t)e * 8 + hp * 2) = make_float2(exv[0], exv[1]);
}

// ---------------- per-node aggregation + output MLP + LayerNorm ----------------
__global__ __launch_bounds__(128) void node_aggr(
    const int* __restrict__ ei,
    const int* __restrict__ off, const int* __restrict__ csr,
    const float* __restrict__ ex_g, const float* __restrict__ Wv_g,
    const float* __restrict__ hv_g,
    const float* __restrict__ wvl_w, const float* __restrict__ wvl_b,
    const float* __restrict__ cen_g,
    const float* __restrict__ out_w, const float* __restrict__ out_b,
    const float* __restrict__ ln_g, const float* __restrict__ ln_b,
    float* __restrict__ out)
{
    const int n = blockIdx.x, t = threadIdx.x;
    const int h = t >> 4, i = t & 15;
    const int base = off[n];
    const int cnt = off[n + 1] - base;

    float d = 0.f;
    for (int j = 0; j < cnt; j++) {
        int e = csr[base + j];
        d += ex_g[(size_t)e * 8 + h];
    }
    float rd = (cnt > 0) ? (1.f / d) : 0.f;

    float S = 0.f;
    for (int j = 0; j < cnt; j++) {
        int e = csr[base + j];
        int c = ei[EE + e];
        float a = ex_g[(size_t)e * 8 + h] * rd;
        S += a * Wv_g[(size_t)e * 16 + i] * hv_g[(size_t)c * 128 + t];
    }

    __shared__ float sl[128];
    __shared__ float vl[128];
    sl[t] = S;
    __syncthreads();
    float agg = (cnt > 0) ? wvl_b[i] : 0.f;
#pragma unroll
    for (int j = 0; j < 16; j++) agg = fmaf(wvl_w[i * 16 + j], sl[h * 16 + j], agg);

    float pre = cen_g[(size_t)n * 128 + t] + agg;
    vl[t] = ssp(pre);
    __syncthreads();

    float acc = out_b[t];
    const float* ow = &out_w[(size_t)t * 128];
#pragma unroll 8
    for (int c = 0; c < 128; c++) acc = fmaf(vl[c], ow[c], acc);

    __shared__ float red[128];
    red[t] = acc;
    __syncthreads();
    for (int s = 64; s > 0; s >>= 1) { if (t < s) red[t] += red[t + s]; __syncthreads(); }
    float mean = red[0] * (1.f / 128.f);
    __syncthreads();
    red[t] = acc * acc;
    __syncthreads();
    for (int s = 64; s > 0; s >>= 1) { if (t < s) red[t] += red[t + s]; __syncthreads(); }
    float var = red[0] * (1.f / 128.f) - mean * mean;
    float inv = rsqrtf(var + 1e-5f);
    out[(size_t)n * 128 + t] = (acc - mean) * inv * ln_g[t] + ln_b[t];
}

extern "C" void kernel_launch(void* const* d_in, const int* in_sizes, int n_in,
                              void* d_out, int out_size, void* d_ws, size_t ws_size,
                              hipStream_t stream)
{
    (void)in_sizes; (void)n_in; (void)out_size; (void)ws_size;
    const float* node_attr = (const float*)d_in[0];
    const int*   edge_index= (const int*)d_in[1];
    const float* edge_attr = (const float*)d_in[2];
    const float* k_w  = (const float*)d_in[3];
    const float* q_w  = (const float*)d_in[4];
    const float* v_w  = (const float*)d_in[5];
    const float* wk1_w= (const float*)d_in[6];  const float* wk1_b= (const float*)d_in[7];
    const float* wk2_w= (const float*)d_in[8];  const float* wk2_b= (const float*)d_in[9];
    const float* wkl_w= (const float*)d_in[10]; const float* wkl_b= (const float*)d_in[11];
    const float* wv1_w= (const float*)d_in[12]; const float* wv1_b= (const float*)d_in[13];
    const float* wv2_w= (const float*)d_in[14]; const float* wv2_b= (const float*)d_in[15];
    const float* wvl_w= (const float*)d_in[16]; const float* wvl_b= (const float*)d_in[17];
    const float* cen_w= (const float*)d_in[18]; const float* cen_b= (const float*)d_in[19];
    const float* out_w= (const float*)d_in[20]; const float* out_b= (const float*)d_in[21];
    const float* ln_g = (const float*)d_in[22]; const float* ln_b = (const float*)d_in[23];
    float* out = (float*)d_out;

    char* ws = (char*)d_ws;
    size_t o = 0;
    auto alloc = [&](size_t bytes) -> void* {
        void* p = ws + o;
        o += (bytes + 255) & ~(size_t)255;
        return p;
    };
    float* hk_g  = (float*)alloc((size_t)NN * 128 * 4);
    float* hv_g  = (float*)alloc((size_t)NN * 128 * 4);
    float* qt_g  = (float*)alloc((size_t)NN * 128 * 4);
    float* cen_g = (float*)alloc((size_t)NN * 128 * 4);
    float* qb_g  = (float*)alloc((size_t)NN * 8 * 4);
    float* Wv_g  = (float*)alloc((size_t)EE * 16 * 4);
    float* ex_g  = (float*)alloc((size_t)EE * 8 * 4);
    int* cnt     = (int*)alloc((size_t)NN * 4);
    int* off     = (int*)alloc((size_t)(NN + 1) * 4);
    int* cursor  = (int*)alloc((size_t)NN * 4);
    int* csr     = (int*)alloc((size_t)EE * 4);

    hipMemsetAsync(cnt, 0, (size_t)NN * 4, stream);

    node_pre<<<NN, 128, 0, stream>>>(node_attr, k_w, q_w, v_w, wkl_w, wkl_b,
                                     cen_w, cen_b, hk_g, hv_g, qt_g, qb_g, cen_g);
    count_kernel<<<(EE + 255) / 256, 256, 0, stream>>>(edge_index, cnt);
    scan_kernel<<<1, 1024, 0, stream>>>(cnt, off, cursor);
    scatter_kernel<<<(EE + 255) / 256, 256, 0, stream>>>(edge_index, cursor, csr);
    edge_fused<<<EE / 64, 256, 0, stream>>>(edge_attr, edge_index,
                                            wk1_w, wk1_b, wk2_w, wk2_b,
                                            wv1_w, wv1_b, wv2_w, wv2_b,
                                            hk_g, qt_g, qb_g, Wv_g, ex_g);
    node_aggr<<<NN, 128, 0, stream>>>(edge_index, off, csr, ex_g, Wv_g, hv_g,
                                      wvl_w, wvl_b, cen_g, out_w, out_b,
                                      ln_g, ln_b, out);
}

// Round 3
// 588.196 us; speedup vs baseline: 1.5539x; 1.2500x over previous
//
#include <hip/hip_runtime.h>
#include <math.h>

#define NN 20000
#define EE 640000
// H=8, Ch=Kh=16, C=K=128, EC=64

typedef __attribute__((ext_vector_type(8))) short short8;
typedef __attribute__((ext_vector_type(4))) float f32x4;

__device__ __forceinline__ float ssp(float x) {
    float sp;
    if (x > 20.f)       sp = x;
    else if (x < -20.f) sp = __expf(x);
    else                sp = log1pf(__expf(x));
    return sp - 0.69314718055994530942f;
}

__device__ __forceinline__ unsigned short f2bf(float f) {
    unsigned u = __float_as_uint(f);
    unsigned r = (u + 0x7FFFu + ((u >> 16) & 1u)) >> 16;
    return (unsigned short)r;
}

__device__ __forceinline__ float4 ld4(const float* p) { return *(const float4*)p; }

__device__ __forceinline__ short8 pack8(float4 p, float4 q) {
    short8 r;
    r[0] = (short)f2bf(p.x); r[1] = (short)f2bf(p.y); r[2] = (short)f2bf(p.z); r[3] = (short)f2bf(p.w);
    r[4] = (short)f2bf(q.x); r[5] = (short)f2bf(q.y); r[6] = (short)f2bf(q.z); r[7] = (short)f2bf(q.w);
    return r;
}

// ---------------- per-node precompute: hkv (bf16 interleaved), q~, qb, cen ----------------
__global__ __launch_bounds__(128) void node_pre(
    const float* __restrict__ node_attr,
    const float* __restrict__ k_w, const float* __restrict__ q_w, const float* __restrict__ v_w,
    const float* __restrict__ wkl_w, const float* __restrict__ wkl_b,
    const float* __restrict__ cen_w, const float* __restrict__ cen_b,
    unsigned int* __restrict__ hkv_g,
    float* __restrict__ qt_g, float* __restrict__ qb_g, float* __restrict__ cen_g)
{
    const int n = blockIdx.x;
    const int t = threadIdx.x;
    __shared__ float x[128];
    __shared__ float hq[128];
    x[t] = node_attr[(size_t)n * 128 + t];
    __syncthreads();
    const int h = t >> 4, i = t & 15;
    const float* xh = &x[h * 16];
    const float* kw = &k_w[h * 256 + i * 16];
    const float* qw = &q_w[h * 256 + i * 16];
    const float* vw = &v_w[h * 256 + i * 16];
    float accK = 0.f, accQ = 0.f, accV = 0.f;
#pragma unroll
    for (int j = 0; j < 16; j++) {
        float xv = xh[j];
        accK = fmaf(xv, kw[j], accK);
        accQ = fmaf(xv, qw[j], accQ);
        accV = fmaf(xv, vw[j], accV);
    }
    // interleaved bf16: lo16 = hk, hi16 = hv
    hkv_g[(size_t)n * 128 + t] = (unsigned int)f2bf(accK) | ((unsigned int)f2bf(accV) << 16);
    hq[t] = accQ;
    __syncthreads();
    float qt = 0.f;
#pragma unroll
    for (int o = 0; o < 16; o++) qt = fmaf(hq[h * 16 + o], wkl_w[o * 16 + i], qt);
    qt_g[(size_t)n * 128 + t] = 0.25f * qt;
    if (i == 0) {
        float qb = 0.f;
#pragma unroll
        for (int o = 0; o < 16; o++) qb = fmaf(hq[h * 16 + o], wkl_b[o], qb);
        qb_g[(size_t)n * 8 + h] = 0.25f * qb;
    }
    float acc = cen_b[t];
    const float* cw = &cen_w[(size_t)t * 128];
#pragma unroll 8
    for (int c = 0; c < 128; c++) acc = fmaf(x[c], cw[c], acc);
    cen_g[(size_t)n * 128 + t] = acc;
}

// ---------------- CSR build ----------------
__global__ void count_kernel(const int* __restrict__ ei, int* __restrict__ cnt) {
    int e = blockIdx.x * 256 + threadIdx.x;
    if (e < EE) atomicAdd(&cnt[ei[e]], 1);
}

__global__ __launch_bounds__(1024) void scan_kernel(const int* __restrict__ cnt,
                                                    int* __restrict__ off, int* __restrict__ cursor) {
    __shared__ int arr[1024];
    const int t = threadIdx.x;
    const int STRIP = 20;
    int start = t * STRIP;
    int end = start + STRIP; if (end > NN) end = NN;
    int local = 0;
    for (int n = start; n < end; n++) local += cnt[n];
    arr[t] = local;
    __syncthreads();
    for (int s = 1; s < 1024; s <<= 1) {
        int v = (t >= s) ? arr[t - s] : 0;
        __syncthreads();
        arr[t] += v;
        __syncthreads();
    }
    int running = arr[t] - local;
    for (int n = start; n < end; n++) {
        off[n] = running;
        cursor[n] = running;
        running += cnt[n];
    }
    if (end == NN) off[NN] = running;
}

// also emits pos[e] (CSR slot of edge e) and csr_col[p] (source node of slot p)
__global__ void scatter_kernel(const int* __restrict__ ei, int* __restrict__ cursor,
                               int* __restrict__ pos_g, int* __restrict__ csr_col) {
    int e = blockIdx.x * 256 + threadIdx.x;
    if (e < EE) {
        int p = atomicAdd(&cursor[ei[e]], 1);
        pos_g[e] = p;
        csr_col[p] = ei[EE + e];
    }
}

// ---------------- edge MLP pass (MFMA, no gathers): Wk/Wv written at CSR slots ----------------
__global__ __launch_bounds__(256) void edge_mlp(
    const float* __restrict__ edge_attr,
    const float* __restrict__ wk1_w, const float* __restrict__ wk1_b,
    const float* __restrict__ wk2_w, const float* __restrict__ wk2_b,
    const float* __restrict__ wv1_w, const float* __restrict__ wv1_b,
    const float* __restrict__ wv2_w, const float* __restrict__ wv2_b,
    const int* __restrict__ pos_g,
    float* __restrict__ Wk_csr, unsigned short* __restrict__ Wv_csr)
{
    __shared__ __align__(16) short lds_k[4][16][16];
    __shared__ __align__(16) short lds_v[4][16][16];

    const int t = threadIdx.x;
    const int wid = t >> 6, lane = t & 63;
    const int row = lane & 15;
    const int kg  = lane >> 4;
    const int e0  = blockIdx.x * 64 + wid * 16;

    const float* ea = edge_attr + (size_t)(e0 + row) * 64 + kg * 8;
    short8 A0 = pack8(ld4(ea),      ld4(ea + 4));
    short8 A1 = pack8(ld4(ea + 32), ld4(ea + 36));

    const float* wkp = wk1_w + row * 64 + kg * 8;
    const float* wvp = wv1_w + row * 64 + kg * 8;
    short8 BK0 = pack8(ld4(wkp),      ld4(wkp + 4));
    short8 BK1 = pack8(ld4(wkp + 32), ld4(wkp + 36));
    short8 BV0 = pack8(ld4(wvp),      ld4(wvp + 4));
    short8 BV1 = pack8(ld4(wvp + 32), ld4(wvp + 36));

    float bk = wk1_b[row], bv = wv1_b[row];
    f32x4 ck = {bk, bk, bk, bk};
    f32x4 cv = {bv, bv, bv, bv};
    ck = __builtin_amdgcn_mfma_f32_16x16x32_bf16(A0, BK0, ck, 0, 0, 0);
    ck = __builtin_amdgcn_mfma_f32_16x16x32_bf16(A1, BK1, ck, 0, 0, 0);
    cv = __builtin_amdgcn_mfma_f32_16x16x32_bf16(A0, BV0, cv, 0, 0, 0);
    cv = __builtin_amdgcn_mfma_f32_16x16x32_bf16(A1, BV1, cv, 0, 0, 0);

#pragma unroll
    for (int r = 0; r < 4; r++) {
        lds_k[wid][kg * 4 + r][row] = (short)f2bf(ssp(ck[r]));
        lds_v[wid][kg * 4 + r][row] = (short)f2bf(ssp(cv[r]));
    }
    __syncthreads();

    short8 A2K = (short8)0, A2V = (short8)0, B2K = (short8)0, B2V = (short8)0;
    if (kg < 2) {
        A2K = *(const short8*)&lds_k[wid][row][kg * 8];
        A2V = *(const short8*)&lds_v[wid][row][kg * 8];
        const float* w2k = wk2_w + row * 16 + kg * 8;
        const float* w2v = wv2_w + row * 16 + kg * 8;
        B2K = pack8(ld4(w2k), ld4(w2k + 4));
        B2V = pack8(ld4(w2v), ld4(w2v + 4));
    }
    float b2k = wk2_b[row], b2v = wv2_b[row];
    f32x4 c2k = {b2k, b2k, b2k, b2k};
    f32x4 c2v = {b2v, b2v, b2v, b2v};
    c2k = __builtin_amdgcn_mfma_f32_16x16x32_bf16(A2K, B2K, c2k, 0, 0, 0);
    c2v = __builtin_amdgcn_mfma_f32_16x16x32_bf16(A2V, B2V, c2v, 0, 0, 0);

#pragma unroll
    for (int r = 0; r < 4; r++) {
        int el = kg * 4 + r;
        int p = pos_g[e0 + el];
        Wk_csr[(size_t)p * 16 + row] = c2k[r];
        Wv_csr[(size_t)p * 16 + row] = f2bf(c2v[r]);
    }
}

// ---------------- fused per-node: qk/exp + aggregation + output MLP + LayerNorm ----------------
__global__ __launch_bounds__(128) void node_fused(
    const int* __restrict__ off, const int* __restrict__ csr_col,
    const float* __restrict__ Wk_csr, const unsigned short* __restrict__ Wv_csr,
    const unsigned int* __restrict__ hkv_g,
    const float* __restrict__ qt_g, const float* __restrict__ qb_g,
    const float* __restrict__ wvl_w, const float* __restrict__ wvl_b,
    const float* __restrict__ cen_g,
    const float* __restrict__ out_w, const float* __restrict__ out_b,
    const float* __restrict__ ln_g, const float* __restrict__ ln_b,
    float* __restrict__ out)
{
    const int n = blockIdx.x, t = threadIdx.x;
    const int h = t >> 4, i = t & 15;
    const int base = off[n];
    const int end  = off[n + 1];
    const int cnt  = end - base;

    const float qtv = qt_g[(size_t)n * 128 + t];
    const float qbh = qb_g[(size_t)n * 8 + h];

    float d = 0.f, U = 0.f;

    int j = base;
    for (; j + 4 <= end; j += 4) {
        int cl[4]; float wk[4]; float wv[4]; unsigned int kv[4];
#pragma unroll
        for (int u = 0; u < 4; u++) cl[u] = csr_col[j + u];
#pragma unroll
        for (int u = 0; u < 4; u++) {
            wk[u] = Wk_csr[(size_t)(j + u) * 16 + i];
            wv[u] = __uint_as_float((unsigned int)Wv_csr[(size_t)(j + u) * 16 + i] << 16);
            kv[u] = hkv_g[(size_t)cl[u] * 128 + t];
        }
#pragma unroll
        for (int u = 0; u < 4; u++) {
            float hk = __uint_as_float(kv[u] << 16);
            float hv = __uint_as_float(kv[u] & 0xFFFF0000u);
            float term = wk[u] * hk * qtv;
            term += __shfl_xor(term, 1);
            term += __shfl_xor(term, 2);
            term += __shfl_xor(term, 4);
            term += __shfl_xor(term, 8);
            float ex = __expf(term + qbh);
            d += ex;
            U = fmaf(ex * wv[u], hv, U);
        }
    }
    for (; j < end; j++) {
        int cl = csr_col[j];
        float wk = Wk_csr[(size_t)j * 16 + i];
        float wv = __uint_as_float((unsigned int)Wv_csr[(size_t)j * 16 + i] << 16);
        unsigned int kv = hkv_g[(size_t)cl * 128 + t];
        float hk = __uint_as_float(kv << 16);
        float hv = __uint_as_float(kv & 0xFFFF0000u);
        float term = wk * hk * qtv;
        term += __shfl_xor(term, 1);
        term += __shfl_xor(term, 2);
        term += __shfl_xor(term, 4);
        term += __shfl_xor(term, 8);
        float ex = __expf(term + qbh);
        d += ex;
        U = fmaf(ex * wv, hv, U);
    }

    float rd = (cnt > 0) ? (1.f / d) : 0.f;
    float S = U * rd;

    __shared__ float sl[128];
    __shared__ float vl[128];
    sl[t] = S;
    __syncthreads();
    float agg = (cnt > 0) ? wvl_b[i] : 0.f;
#pragma unroll
    for (int jj = 0; jj < 16; jj++) agg = fmaf(wvl_w[i * 16 + jj], sl[h * 16 + jj], agg);

    float pre = cen_g[(size_t)n * 128 + t] + agg;
    vl[t] = ssp(pre);
    __syncthreads();

    float acc = out_b[t];
    const float* ow = &out_w[(size_t)t * 128];
#pragma unroll 8
    for (int c = 0; c < 128; c++) acc = fmaf(vl[c], ow[c], acc);

    __shared__ float red[128];
    red[t] = acc;
    __syncthreads();
    for (int s = 64; s > 0; s >>= 1) { if (t < s) red[t] += red[t + s]; __syncthreads(); }
    float mean = red[0] * (1.f / 128.f);
    __syncthreads();
    red[t] = acc * acc;
    __syncthreads();
    for (int s = 64; s > 0; s >>= 1) { if (t < s) red[t] += red[t + s]; __syncthreads(); }
    float var = red[0] * (1.f / 128.f) - mean * mean;
    float inv = rsqrtf(var + 1e-5f);
    out[(size_t)n * 128 + t] = (acc - mean) * inv * ln_g[t] + ln_b[t];
}

extern "C" void kernel_launch(void* const* d_in, const int* in_sizes, int n_in,
                              void* d_out, int out_size, void* d_ws, size_t ws_size,
                              hipStream_t stream)
{
    (void)in_sizes; (void)n_in; (void)out_size; (void)ws_size;
    const float* node_attr = (const float*)d_in[0];
    const int*   edge_index= (const int*)d_in[1];
    const float* edge_attr = (const float*)d_in[2];
    const float* k_w  = (const float*)d_in[3];
    const float* q_w  = (const float*)d_in[4];
    const float* v_w  = (const float*)d_in[5];
    const float* wk1_w= (const float*)d_in[6];  const float* wk1_b= (const float*)d_in[7];
    const float* wk2_w= (const float*)d_in[8];  const float* wk2_b= (const float*)d_in[9];
    const float* wkl_w= (const float*)d_in[10]; const float* wkl_b= (const float*)d_in[11];
    const float* wv1_w= (const float*)d_in[12]; const float* wv1_b= (const float*)d_in[13];
    const float* wv2_w= (const float*)d_in[14]; const float* wv2_b= (const float*)d_in[15];
    const float* wvl_w= (const float*)d_in[16]; const float* wvl_b= (const float*)d_in[17];
    const float* cen_w= (const float*)d_in[18]; const float* cen_b= (const float*)d_in[19];
    const float* out_w= (const float*)d_in[20]; const float* out_b= (const float*)d_in[21];
    const float* ln_g = (const float*)d_in[22]; const float* ln_b = (const float*)d_in[23];
    float* out = (float*)d_out;

    char* ws = (char*)d_ws;
    size_t o = 0;
    auto alloc = [&](size_t bytes) -> void* {
        void* p = ws + o;
        o += (bytes + 255) & ~(size_t)255;
        return p;
    };
    unsigned int*  hkv_g = (unsigned int*)alloc((size_t)NN * 128 * 4);
    float* qt_g  = (float*)alloc((size_t)NN * 128 * 4);
    float* cen_g = (float*)alloc((size_t)NN * 128 * 4);
    float* qb_g  = (float*)alloc((size_t)NN * 8 * 4);
    float* Wk_csr = (float*)alloc((size_t)EE * 16 * 4);
    unsigned short* Wv_csr = (unsigned short*)alloc((size_t)EE * 16 * 2);
    int* cnt     = (int*)alloc((size_t)NN * 4);
    int* off     = (int*)alloc((size_t)(NN + 1) * 4);
    int* cursor  = (int*)alloc((size_t)NN * 4);
    int* pos_g   = (int*)alloc((size_t)EE * 4);
    int* csr_col = (int*)alloc((size_t)EE * 4);

    hipMemsetAsync(cnt, 0, (size_t)NN * 4, stream);

    node_pre<<<NN, 128, 0, stream>>>(node_attr, k_w, q_w, v_w, wkl_w, wkl_b,
                                     cen_w, cen_b, hkv_g, qt_g, qb_g, cen_g);
    count_kernel<<<(EE + 255) / 256, 256, 0, stream>>>(edge_index, cnt);
    scan_kernel<<<1, 1024, 0, stream>>>(cnt, off, cursor);
    scatter_kernel<<<(EE + 255) / 256, 256, 0, stream>>>(edge_index, cursor, pos_g, csr_col);
    edge_mlp<<<EE / 64, 256, 0, stream>>>(edge_attr,
                                          wk1_w, wk1_b, wk2_w, wk2_b,
                                          wv1_w, wv1_b, wv2_w, wv2_b,
                                          pos_g, Wk_csr, Wv_csr);
    node_fused<<<NN, 128, 0, stream>>>(off, csr_col, Wk_csr, Wv_csr, hkv_g,
                                       qt_g, qb_g, wvl_w, wvl_b, cen_g,
                                       out_w, out_b, ln_g, ln_b, out);
}

// Round 4
// 572.211 us; speedup vs baseline: 1.5973x; 1.0279x over previous
//
#include <hip/hip_runtime.h>
#include <math.h>

#define NN 20000
#define EE 640000
// H=8, Ch=Kh=16, C=K=128, EC=64

typedef __attribute__((ext_vector_type(8))) short short8;
typedef __attribute__((ext_vector_type(4))) float f32x4;

__device__ __forceinline__ float ssp(float x) {
    float sp;
    if (x > 20.f)       sp = x;
    else if (x < -20.f) sp = __expf(x);
    else                sp = log1pf(__expf(x));
    return sp - 0.69314718055994530942f;
}

__device__ __forceinline__ unsigned short f2bf(float f) {
    unsigned u = __float_as_uint(f);
    unsigned r = (u + 0x7FFFu + ((u >> 16) & 1u)) >> 16;
    return (unsigned short)r;
}

__device__ __forceinline__ float4 ld4(const float* p) { return *(const float4*)p; }

__device__ __forceinline__ short8 pack8(float4 p, float4 q) {
    short8 r;
    r[0] = (short)f2bf(p.x); r[1] = (short)f2bf(p.y); r[2] = (short)f2bf(p.z); r[3] = (short)f2bf(p.w);
    r[4] = (short)f2bf(q.x); r[5] = (short)f2bf(q.y); r[6] = (short)f2bf(q.z); r[7] = (short)f2bf(q.w);
    return r;
}

// sum across each 16-lane row via DPP rotate-adds (pure VALU, no DS/lgkm waits)
__device__ __forceinline__ float rowsum16(float x) {
    x += __int_as_float(__builtin_amdgcn_update_dpp(0, __float_as_int(x), 0x121, 0xF, 0xF, true));
    x += __int_as_float(__builtin_amdgcn_update_dpp(0, __float_as_int(x), 0x122, 0xF, 0xF, true));
    x += __int_as_float(__builtin_amdgcn_update_dpp(0, __float_as_int(x), 0x124, 0xF, 0xF, true));
    x += __int_as_float(__builtin_amdgcn_update_dpp(0, __float_as_int(x), 0x128, 0xF, 0xF, true));
    return x;
}

// ---------------- per-node precompute: hkv (bf16 interleaved), q~, qb, cen ----------------
__global__ __launch_bounds__(128) void node_pre(
    const float* __restrict__ node_attr,
    const float* __restrict__ k_w, const float* __restrict__ q_w, const float* __restrict__ v_w,
    const float* __restrict__ wkl_w, const float* __restrict__ wkl_b,
    const float* __restrict__ cen_w, const float* __restrict__ cen_b,
    unsigned int* __restrict__ hkv_g,
    float* __restrict__ qt_g, float* __restrict__ qb_g, float* __restrict__ cen_g)
{
    const int n = blockIdx.x;
    const int t = threadIdx.x;
    __shared__ float x[128];
    __shared__ float hq[128];
    x[t] = node_attr[(size_t)n * 128 + t];
    __syncthreads();
    const int h = t >> 4, i = t & 15;
    const float* xh = &x[h * 16];
    const float* kw = &k_w[h * 256 + i * 16];
    const float* qw = &q_w[h * 256 + i * 16];
    const float* vw = &v_w[h * 256 + i * 16];
    float accK = 0.f, accQ = 0.f, accV = 0.f;
#pragma unroll
    for (int j = 0; j < 16; j++) {
        float xv = xh[j];
        accK = fmaf(xv, kw[j], accK);
        accQ = fmaf(xv, qw[j], accQ);
        accV = fmaf(xv, vw[j], accV);
    }
    hkv_g[(size_t)n * 128 + t] = (unsigned int)f2bf(accK) | ((unsigned int)f2bf(accV) << 16);
    hq[t] = accQ;
    __syncthreads();
    float qt = 0.f;
#pragma unroll
    for (int o = 0; o < 16; o++) qt = fmaf(hq[h * 16 + o], wkl_w[o * 16 + i], qt);
    qt_g[(size_t)n * 128 + t] = 0.25f * qt;
    if (i == 0) {
        float qb = 0.f;
#pragma unroll
        for (int o = 0; o < 16; o++) qb = fmaf(hq[h * 16 + o], wkl_b[o], qb);
        qb_g[(size_t)n * 8 + h] = 0.25f * qb;
    }
    float acc = cen_b[t];
    const float* cw = &cen_w[(size_t)t * 128];
#pragma unroll 8
    for (int c = 0; c < 128; c++) acc = fmaf(x[c], cw[c], acc);
    cen_g[(size_t)n * 128 + t] = acc;
}

// ---------------- CSR build ----------------
__global__ void count_kernel(const int* __restrict__ ei, int* __restrict__ cnt) {
    int e = blockIdx.x * 256 + threadIdx.x;
    if (e < EE) atomicAdd(&cnt[ei[e]], 1);
}

__global__ __launch_bounds__(1024) void scan_kernel(const int* __restrict__ cnt,
                                                    int* __restrict__ off, int* __restrict__ cursor) {
    __shared__ int arr[1024];
    const int t = threadIdx.x;
    const int STRIP = 20;
    int start = t * STRIP;
    int end = start + STRIP; if (end > NN) end = NN;
    int local = 0;
    for (int n = start; n < end; n++) local += cnt[n];
    arr[t] = local;
    __syncthreads();
    for (int s = 1; s < 1024; s <<= 1) {
        int v = (t >= s) ? arr[t - s] : 0;
        __syncthreads();
        arr[t] += v;
        __syncthreads();
    }
    int running = arr[t] - local;
    for (int n = start; n < end; n++) {
        off[n] = running;
        cursor[n] = running;
        running += cnt[n];
    }
    if (end == NN) off[NN] = running;
}

__global__ void scatter_kernel(const int* __restrict__ ei, int* __restrict__ cursor,
                               int* __restrict__ pos_g, int* __restrict__ csr_col) {
    int e = blockIdx.x * 256 + threadIdx.x;
    if (e < EE) {
        int p = atomicAdd(&cursor[ei[e]], 1);
        pos_g[e] = p;
        csr_col[p] = ei[EE + e];
    }
}

// ---------------- edge MLP pass (MFMA, no gathers): packed Wk|Wv bf16 at CSR slots ----------------
__global__ __launch_bounds__(256) void edge_mlp(
    const float* __restrict__ edge_attr,
    const float* __restrict__ wk1_w, const float* __restrict__ wk1_b,
    const float* __restrict__ wk2_w, const float* __restrict__ wk2_b,
    const float* __restrict__ wv1_w, const float* __restrict__ wv1_b,
    const float* __restrict__ wv2_w, const float* __restrict__ wv2_b,
    const int* __restrict__ pos_g,
    unsigned int* __restrict__ wkv_csr)
{
    __shared__ __align__(16) short lds_k[4][16][16];
    __shared__ __align__(16) short lds_v[4][16][16];

    const int t = threadIdx.x;
    const int wid = t >> 6, lane = t & 63;
    const int row = lane & 15;
    const int kg  = lane >> 4;
    const int e0  = blockIdx.x * 64 + wid * 16;

    const float* ea = edge_attr + (size_t)(e0 + row) * 64 + kg * 8;
    short8 A0 = pack8(ld4(ea),      ld4(ea + 4));
    short8 A1 = pack8(ld4(ea + 32), ld4(ea + 36));

    const float* wkp = wk1_w + row * 64 + kg * 8;
    const float* wvp = wv1_w + row * 64 + kg * 8;
    short8 BK0 = pack8(ld4(wkp),      ld4(wkp + 4));
    short8 BK1 = pack8(ld4(wkp + 32), ld4(wkp + 36));
    short8 BV0 = pack8(ld4(wvp),      ld4(wvp + 4));
    short8 BV1 = pack8(ld4(wvp + 32), ld4(wvp + 36));

    float bk = wk1_b[row], bv = wv1_b[row];
    f32x4 ck = {bk, bk, bk, bk};
    f32x4 cv = {bv, bv, bv, bv};
    ck = __builtin_amdgcn_mfma_f32_16x16x32_bf16(A0, BK0, ck, 0, 0, 0);
    ck = __builtin_amdgcn_mfma_f32_16x16x32_bf16(A1, BK1, ck, 0, 0, 0);
    cv = __builtin_amdgcn_mfma_f32_16x16x32_bf16(A0, BV0, cv, 0, 0, 0);
    cv = __builtin_amdgcn_mfma_f32_16x16x32_bf16(A1, BV1, cv, 0, 0, 0);

#pragma unroll
    for (int r = 0; r < 4; r++) {
        lds_k[wid][kg * 4 + r][row] = (short)f2bf(ssp(ck[r]));
        lds_v[wid][kg * 4 + r][row] = (short)f2bf(ssp(cv[r]));
    }
    __syncthreads();

    short8 A2K = (short8)0, A2V = (short8)0, B2K = (short8)0, B2V = (short8)0;
    if (kg < 2) {
        A2K = *(const short8*)&lds_k[wid][row][kg * 8];
        A2V = *(const short8*)&lds_v[wid][row][kg * 8];
        const float* w2k = wk2_w + row * 16 + kg * 8;
        const float* w2v = wv2_w + row * 16 + kg * 8;
        B2K = pack8(ld4(w2k), ld4(w2k + 4));
        B2V = pack8(ld4(w2v), ld4(w2v + 4));
    }
    float b2k = wk2_b[row], b2v = wv2_b[row];
    f32x4 c2k = {b2k, b2k, b2k, b2k};
    f32x4 c2v = {b2v, b2v, b2v, b2v};
    c2k = __builtin_amdgcn_mfma_f32_16x16x32_bf16(A2K, B2K, c2k, 0, 0, 0);
    c2v = __builtin_amdgcn_mfma_f32_16x16x32_bf16(A2V, B2V, c2v, 0, 0, 0);

#pragma unroll
    for (int r = 0; r < 4; r++) {
        int el = kg * 4 + r;
        int p = pos_g[e0 + el];
        wkv_csr[(size_t)p * 16 + row] =
            (unsigned int)f2bf(c2k[r]) | ((unsigned int)f2bf(c2v[r]) << 16);
    }
}

// ---------------- fused per-node: qk/exp + aggregation + output MLP + LayerNorm ----------------
__global__ __launch_bounds__(128) void node_fused(
    const int* __restrict__ off, const int* __restrict__ csr_col,
    const unsigned int* __restrict__ wkv_csr,
    const unsigned int* __restrict__ hkv_g,
    const float* __restrict__ qt_g, const float* __restrict__ qb_g,
    const float* __restrict__ wvl_w, const float* __restrict__ wvl_b,
    const float* __restrict__ cen_g,
    const float* __restrict__ out_w, const float* __restrict__ out_b,
    const float* __restrict__ ln_g, const float* __restrict__ ln_b,
    float* __restrict__ out)
{
    const int n = blockIdx.x, t = threadIdx.x;
    const int h = t >> 4, i = t & 15;
    const int base = off[n];
    const int end  = off[n + 1];
    const int cnt  = end - base;

    const float qtv = qt_g[(size_t)n * 128 + t];
    const float qbh = qb_g[(size_t)n * 8 + h];

    float d = 0.f, U = 0.f;

    int j = base;
    for (; j + 8 <= end; j += 8) {
        int cl[8]; unsigned int wkv[8]; unsigned int kv[8];
#pragma unroll
        for (int u = 0; u < 8; u++) cl[u] = csr_col[j + u];
#pragma unroll
        for (int u = 0; u < 8; u++) {
            wkv[u] = wkv_csr[(size_t)(j + u) * 16 + i];
            kv[u]  = hkv_g[(size_t)cl[u] * 128 + t];
        }
#pragma unroll
        for (int u = 0; u < 8; u++) {
            float hk = __uint_as_float(kv[u] << 16);
            float hv = __uint_as_float(kv[u] & 0xFFFF0000u);
            float wk = __uint_as_float(wkv[u] << 16);
            float wv = __uint_as_float(wkv[u] & 0xFFFF0000u);
            float term = rowsum16(wk * hk * qtv);
            float ex = __expf(term + qbh);
            d += ex;
            U = fmaf(ex * wv, hv, U);
        }
    }
    for (; j < end; j++) {
        int cl = csr_col[j];
        unsigned int wkv = wkv_csr[(size_t)j * 16 + i];
        unsigned int kv  = hkv_g[(size_t)cl * 128 + t];
        float hk = __uint_as_float(kv << 16);
        float hv = __uint_as_float(kv & 0xFFFF0000u);
        float wk = __uint_as_float(wkv << 16);
        float wv = __uint_as_float(wkv & 0xFFFF0000u);
        float term = rowsum16(wk * hk * qtv);
        float ex = __expf(term + qbh);
        d += ex;
        U = fmaf(ex * wv, hv, U);
    }

    float rd = (cnt > 0) ? (1.f / d) : 0.f;
    float S = U * rd;

    __shared__ float sl[128];
    __shared__ float vl[128];
    sl[t] = S;
    __syncthreads();
    float agg = (cnt > 0) ? wvl_b[i] : 0.f;
#pragma unroll
    for (int jj = 0; jj < 16; jj++) agg = fmaf(wvl_w[i * 16 + jj], sl[h * 16 + jj], agg);

    float pre = cen_g[(size_t)n * 128 + t] + agg;
    vl[t] = ssp(pre);
    __syncthreads();

    float acc = out_b[t];
    const float* ow = &out_w[(size_t)t * 128];
#pragma unroll 8
    for (int c = 0; c < 128; c++) acc = fmaf(vl[c], ow[c], acc);

    __shared__ float red[128];
    red[t] = acc;
    __syncthreads();
    for (int s = 64; s > 0; s >>= 1) { if (t < s) red[t] += red[t + s]; __syncthreads(); }
    float mean = red[0] * (1.f / 128.f);
    __syncthreads();
    red[t] = acc * acc;
    __syncthreads();
    for (int s = 64; s > 0; s >>= 1) { if (t < s) red[t] += red[t + s]; __syncthreads(); }
    float var = red[0] * (1.f / 128.f) - mean * mean;
    float inv = rsqrtf(var + 1e-5f);
    out[(size_t)n * 128 + t] = (acc - mean) * inv * ln_g[t] + ln_b[t];
}

extern "C" void kernel_launch(void* const* d_in, const int* in_sizes, int n_in,
                              void* d_out, int out_size, void* d_ws, size_t ws_size,
                              hipStream_t stream)
{
    (void)in_sizes; (void)n_in; (void)out_size; (void)ws_size;
    const float* node_attr = (const float*)d_in[0];
    const int*   edge_index= (const int*)d_in[1];
    const float* edge_attr = (const float*)d_in[2];
    const float* k_w  = (const float*)d_in[3];
    const float* q_w  = (const float*)d_in[4];
    const float* v_w  = (const float*)d_in[5];
    const float* wk1_w= (const float*)d_in[6];  const float* wk1_b= (const float*)d_in[7];
    const float* wk2_w= (const float*)d_in[8];  const float* wk2_b= (const float*)d_in[9];
    const float* wkl_w= (const float*)d_in[10]; const float* wkl_b= (const float*)d_in[11];
    const float* wv1_w= (const float*)d_in[12]; const float* wv1_b= (const float*)d_in[13];
    const float* wv2_w= (const float*)d_in[14]; const float* wv2_b= (const float*)d_in[15];
    const float* wvl_w= (const float*)d_in[16]; const float* wvl_b= (const float*)d_in[17];
    const float* cen_w= (const float*)d_in[18]; const float* cen_b= (const float*)d_in[19];
    const float* out_w= (const float*)d_in[20]; const float* out_b= (const float*)d_in[21];
    const float* ln_g = (const float*)d_in[22]; const float* ln_b = (const float*)d_in[23];
    float* out = (float*)d_out;

    char* ws = (char*)d_ws;
    size_t o = 0;
    auto alloc = [&](size_t bytes) -> void* {
        void* p = ws + o;
        o += (bytes + 255) & ~(size_t)255;
        return p;
    };
    unsigned int*  hkv_g = (unsigned int*)alloc((size_t)NN * 128 * 4);
    float* qt_g  = (float*)alloc((size_t)NN * 128 * 4);
    float* cen_g = (float*)alloc((size_t)NN * 128 * 4);
    float* qb_g  = (float*)alloc((size_t)NN * 8 * 4);
    unsigned int* wkv_csr = (unsigned int*)alloc((size_t)EE * 16 * 4);
    int* cnt     = (int*)alloc((size_t)NN * 4);
    int* off     = (int*)alloc((size_t)(NN + 1) * 4);
    int* cursor  = (int*)alloc((size_t)NN * 4);
    int* pos_g   = (int*)alloc((size_t)EE * 4);
    int* csr_col = (int*)alloc((size_t)EE * 4);

    hipMemsetAsync(cnt, 0, (size_t)NN * 4, stream);

    node_pre<<<NN, 128, 0, stream>>>(node_attr, k_w, q_w, v_w, wkl_w, wkl_b,
                                     cen_w, cen_b, hkv_g, qt_g, qb_g, cen_g);
    count_kernel<<<(EE + 255) / 256, 256, 0, stream>>>(edge_index, cnt);
    scan_kernel<<<1, 1024, 0, stream>>>(cnt, off, cursor);
    scatter_kernel<<<(EE + 255) / 256, 256, 0, stream>>>(edge_index, cursor, pos_g, csr_col);
    edge_mlp<<<EE / 64, 256, 0, stream>>>(edge_attr,
                                          wk1_w, wk1_b, wk2_w, wk2_b,
                                          wv1_w, wv1_b, wv2_w, wv2_b,
                                          pos_g, wkv_csr);
    node_fused<<<NN, 128, 0, stream>>>(off, csr_col, wkv_csr, hkv_g,
                                       qt_g, qb_g, wvl_w, wvl_b, cen_g,
                                       out_w, out_b, ln_g, ln_b, out);
}

// Round 5
// 556.018 us; speedup vs baseline: 1.6439x; 1.0291x over previous
//
#include <hip/hip_runtime.h>
#include <math.h>

#define NN 20000
#define EE 640000
// H=8, Ch=Kh=16, C=K=128, EC=64

typedef __attribute__((ext_vector_type(8))) short short8;
typedef __attribute__((ext_vector_type(4))) float f32x4;

__device__ __forceinline__ float ssp(float x) {
    float sp;
    if (x > 20.f)       sp = x;
    else if (x < -20.f) sp = __expf(x);
    else                sp = log1pf(__expf(x));
    return sp - 0.69314718055994530942f;
}

__device__ __forceinline__ unsigned short f2bf(float f) {
    unsigned u = __float_as_uint(f);
    unsigned r = (u + 0x7FFFu + ((u >> 16) & 1u)) >> 16;
    return (unsigned short)r;
}

__device__ __forceinline__ float4 ld4(const float* p) { return *(const float4*)p; }

__device__ __forceinline__ short8 pack8(float4 p, float4 q) {
    short8 r;
    r[0] = (short)f2bf(p.x); r[1] = (short)f2bf(p.y); r[2] = (short)f2bf(p.z); r[3] = (short)f2bf(p.w);
    r[4] = (short)f2bf(q.x); r[5] = (short)f2bf(q.y); r[6] = (short)f2bf(q.z); r[7] = (short)f2bf(q.w);
    return r;
}

// ---------------- one-time bf16 weight packing ----------------
__global__ __launch_bounds__(256) void prep_w(
    const float* __restrict__ wk1_w, const float* __restrict__ wv1_w,
    const float* __restrict__ wk2_w, const float* __restrict__ wv2_w,
    short* __restrict__ w1k, short* __restrict__ w1v,
    short* __restrict__ w2k, short* __restrict__ w2v)
{
    const int t = threadIdx.x;
    for (int idx = t; idx < 1024; idx += 256) {
        w1k[idx] = (short)f2bf(wk1_w[idx]);
        w1v[idx] = (short)f2bf(wv1_w[idx]);
    }
    if (t < 256) {
        w2k[t] = (short)f2bf(wk2_w[t]);
        w2v[t] = (short)f2bf(wv2_w[t]);
    }
}

// ---------------- per-node precompute: hkv (bf16 interleaved), q~, qb, cen ----------------
__global__ __launch_bounds__(128) void node_pre(
    const float* __restrict__ node_attr,
    const float* __restrict__ k_w, const float* __restrict__ q_w, const float* __restrict__ v_w,
    const float* __restrict__ wkl_w, const float* __restrict__ wkl_b,
    const float* __restrict__ cen_w, const float* __restrict__ cen_b,
    unsigned int* __restrict__ hkv_g,
    float* __restrict__ qt_g, float* __restrict__ qb_g, float* __restrict__ cen_g)
{
    const int n = blockIdx.x;
    const int t = threadIdx.x;
    __shared__ float x[128];
    __shared__ float hq[128];
    x[t] = node_attr[(size_t)n * 128 + t];
    __syncthreads();
    const int h = t >> 4, i = t & 15;
    const float* xh = &x[h * 16];
    const float* kw = &k_w[h * 256 + i * 16];
    const float* qw = &q_w[h * 256 + i * 16];
    const float* vw = &v_w[h * 256 + i * 16];
    float accK = 0.f, accQ = 0.f, accV = 0.f;
#pragma unroll
    for (int j = 0; j < 16; j++) {
        float xv = xh[j];
        accK = fmaf(xv, kw[j], accK);
        accQ = fmaf(xv, qw[j], accQ);
        accV = fmaf(xv, vw[j], accV);
    }
    hkv_g[(size_t)n * 128 + t] = (unsigned int)f2bf(accK) | ((unsigned int)f2bf(accV) << 16);
    hq[t] = accQ;
    __syncthreads();
    float qt = 0.f;
#pragma unroll
    for (int o = 0; o < 16; o++) qt = fmaf(hq[h * 16 + o], wkl_w[o * 16 + i], qt);
    qt_g[(size_t)n * 128 + t] = 0.25f * qt;
    if (i == 0) {
        float qb = 0.f;
#pragma unroll
        for (int o = 0; o < 16; o++) qb = fmaf(hq[h * 16 + o], wkl_b[o], qb);
        qb_g[(size_t)n * 8 + h] = 0.25f * qb;
    }
    float acc = cen_b[t];
    const float* cw = &cen_w[(size_t)t * 128];
#pragma unroll 8
    for (int c = 0; c < 128; c++) acc = fmaf(x[c], cw[c], acc);
    cen_g[(size_t)n * 128 + t] = acc;
}

// ---------------- CSR build ----------------
__global__ void count_kernel(const int* __restrict__ ei, int* __restrict__ cnt) {
    int e = blockIdx.x * 256 + threadIdx.x;
    if (e < EE) atomicAdd(&cnt[ei[e]], 1);
}

__global__ __launch_bounds__(1024) void scan_kernel(const int* __restrict__ cnt,
                                                    int* __restrict__ off, int* __restrict__ cursor) {
    __shared__ int arr[1024];
    const int t = threadIdx.x;
    const int STRIP = 20;
    int start = t * STRIP;
    int end = start + STRIP; if (end > NN) end = NN;
    int local = 0;
    for (int n = start; n < end; n++) local += cnt[n];
    arr[t] = local;
    __syncthreads();
    for (int s = 1; s < 1024; s <<= 1) {
        int v = (t >= s) ? arr[t - s] : 0;
        __syncthreads();
        arr[t] += v;
        __syncthreads();
    }
    int running = arr[t] - local;
    for (int n = start; n < end; n++) {
        off[n] = running;
        cursor[n] = running;
        running += cnt[n];
    }
    if (end == NN) off[NN] = running;
}

// emits csr_e[p] = e (for CSR-ordered edge_mlp) and csr_col[p] = source node
__global__ void scatter_kernel(const int* __restrict__ ei, int* __restrict__ cursor,
                               int* __restrict__ csr_e, int* __restrict__ csr_col) {
    int e = blockIdx.x * 256 + threadIdx.x;
    if (e < EE) {
        int p = atomicAdd(&cursor[ei[e]], 1);
        csr_e[p] = e;
        csr_col[p] = ei[EE + e];
    }
}

// ---------------- edge MLP pass (MFMA), CSR order: gathered reads, sequential writes ----------------
__global__ __launch_bounds__(256) void edge_mlp(
    const float* __restrict__ edge_attr,
    const short* __restrict__ w1k, const float* __restrict__ wk1_b,
    const short* __restrict__ w2k, const float* __restrict__ wk2_b,
    const short* __restrict__ w1v, const float* __restrict__ wv1_b,
    const short* __restrict__ w2v, const float* __restrict__ wv2_b,
    const int* __restrict__ csr_e,
    unsigned int* __restrict__ wkv_csr)
{
    __shared__ __align__(16) short lds_k[4][16][16];
    __shared__ __align__(16) short lds_v[4][16][16];

    const int t = threadIdx.x;
    const int wid = t >> 6, lane = t & 63;
    const int row = lane & 15;
    const int kg  = lane >> 4;
    const int e0  = blockIdx.x * 64 + wid * 16;   // CSR slots

    const int src = csr_e[e0 + row];
    const float* ea = edge_attr + (size_t)src * 64 + kg * 8;
    short8 A0 = pack8(ld4(ea),      ld4(ea + 4));
    short8 A1 = pack8(ld4(ea + 32), ld4(ea + 36));

    short8 BK0 = *(const short8*)(w1k + row * 64 + kg * 8);
    short8 BK1 = *(const short8*)(w1k + row * 64 + kg * 8 + 32);
    short8 BV0 = *(const short8*)(w1v + row * 64 + kg * 8);
    short8 BV1 = *(const short8*)(w1v + row * 64 + kg * 8 + 32);

    float bk = wk1_b[row], bv = wv1_b[row];
    f32x4 ck = {bk, bk, bk, bk};
    f32x4 cv = {bv, bv, bv, bv};
    ck = __builtin_amdgcn_mfma_f32_16x16x32_bf16(A0, BK0, ck, 0, 0, 0);
    ck = __builtin_amdgcn_mfma_f32_16x16x32_bf16(A1, BK1, ck, 0, 0, 0);
    cv = __builtin_amdgcn_mfma_f32_16x16x32_bf16(A0, BV0, cv, 0, 0, 0);
    cv = __builtin_amdgcn_mfma_f32_16x16x32_bf16(A1, BV1, cv, 0, 0, 0);

#pragma unroll
    for (int r = 0; r < 4; r++) {
        lds_k[wid][kg * 4 + r][row] = (short)f2bf(ssp(ck[r]));
        lds_v[wid][kg * 4 + r][row] = (short)f2bf(ssp(cv[r]));
    }
    __syncthreads();

    short8 A2K = (short8)0, A2V = (short8)0, B2K = (short8)0, B2V = (short8)0;
    if (kg < 2) {
        A2K = *(const short8*)&lds_k[wid][row][kg * 8];
        A2V = *(const short8*)&lds_v[wid][row][kg * 8];
        B2K = *(const short8*)(w2k + row * 16 + kg * 8);
        B2V = *(const short8*)(w2v + row * 16 + kg * 8);
    }
    float b2k = wk2_b[row], b2v = wv2_b[row];
    f32x4 c2k = {b2k, b2k, b2k, b2k};
    f32x4 c2v = {b2v, b2v, b2v, b2v};
    c2k = __builtin_amdgcn_mfma_f32_16x16x32_bf16(A2K, B2K, c2k, 0, 0, 0);
    c2v = __builtin_amdgcn_mfma_f32_16x16x32_bf16(A2V, B2V, c2v, 0, 0, 0);

    // sequential (CSR-slot-ordered) packed writes
#pragma unroll
    for (int r = 0; r < 4; r++) {
        int el = kg * 4 + r;
        wkv_csr[(size_t)(e0 + el) * 16 + row] =
            (unsigned int)f2bf(c2k[r]) | ((unsigned int)f2bf(c2v[r]) << 16);
    }
}

// ---------------- fused per-node: lane-per-(edge,head) attention + epilogue ----------------
// 128 threads = 2 independent waves, one node per wave. lane = eslot*8 + h.
__global__ __launch_bounds__(128) void node_fused(
    const int* __restrict__ off, const int* __restrict__ csr_col,
    const unsigned int* __restrict__ wkv_csr,
    const unsigned int* __restrict__ hkv_g,
    const float* __restrict__ qt_g, const float* __restrict__ qb_g,
    const float* __restrict__ wvl_w, const float* __restrict__ wvl_b,
    const float* __restrict__ cen_g,
    const float* __restrict__ out_w, const float* __restrict__ out_b,
    const float* __restrict__ ln_g, const float* __restrict__ ln_b,
    float* __restrict__ out)
{
    __shared__ float S_lds[2][128];
    __shared__ float vl_lds[2][128];

    const int wave = threadIdx.x >> 6;
    const int lane = threadIdx.x & 63;
    const int n = blockIdx.x * 2 + wave;
    const int eslot = lane >> 3;   // 0..7 edge slot
    const int h     = lane & 7;    // head

    const int base = off[n];
    const int end  = off[n + 1];

    // loop-invariant per-lane query state
    float qt[16];
    {
        const float* q = qt_g + (size_t)n * 128 + h * 16;
        *(float4*)(qt + 0)  = ld4(q + 0);
        *(float4*)(qt + 4)  = ld4(q + 4);
        *(float4*)(qt + 8)  = ld4(q + 8);
        *(float4*)(qt + 12) = ld4(q + 12);
    }
    const float qbh = qb_g[(size_t)n * 8 + h];

    float U[16];
#pragma unroll
    for (int i = 0; i < 16; i++) U[i] = 0.f;
    float d = 0.f;

    for (int j0 = base; j0 < end; j0 += 8) {
        const int myj = j0 + eslot;
        const bool valid = myj < end;
        const int jj = valid ? myj : base;
        const int cl = csr_col[jj];

        unsigned int kv[16], wv[16];
        {
            const unsigned int* kp = hkv_g + (size_t)cl * 128 + h * 16;
            *(uint4*)(kv + 0)  = *(const uint4*)(kp + 0);
            *(uint4*)(kv + 4)  = *(const uint4*)(kp + 4);
            *(uint4*)(kv + 8)  = *(const uint4*)(kp + 8);
            *(uint4*)(kv + 12) = *(const uint4*)(kp + 12);
            const unsigned int* wp = wkv_csr + (size_t)jj * 16;
            *(uint4*)(wv + 0)  = *(const uint4*)(wp + 0);
            *(uint4*)(wv + 4)  = *(const uint4*)(wp + 4);
            *(uint4*)(wv + 8)  = *(const uint4*)(wp + 8);
            *(uint4*)(wv + 12) = *(const uint4*)(wp + 12);
        }

        float term = 0.f;
        float uv[16];
#pragma unroll
        for (int i = 0; i < 16; i++) {
            float hk  = __uint_as_float(kv[i] << 16);
            float wkf = __uint_as_float(wv[i] << 16);
            float hv  = __uint_as_float(kv[i] & 0xFFFF0000u);
            float wvf = __uint_as_float(wv[i] & 0xFFFF0000u);
            term = fmaf(wkf * hk, qt[i], term);
            uv[i] = wvf * hv;
        }
        float ex = __expf(term + qbh);
        ex = valid ? ex : 0.f;
        d += ex;
#pragma unroll
        for (int i = 0; i < 16; i++) U[i] = fmaf(ex, uv[i], U[i]);
    }

    // once-per-node cross-lane reduction over the 8 edge slots (strides 8,16,32)
#pragma unroll
    for (int s = 8; s <= 32; s <<= 1) {
        d += __shfl_xor(d, s);
#pragma unroll
        for (int i = 0; i < 16; i++) U[i] += __shfl_xor(U[i], s);
    }

    const float rd = (base < end) ? (1.f / d) : 0.f;
    if (lane < 8) {
#pragma unroll
        for (int i = 0; i < 16; i++) S_lds[wave][lane * 16 + i] = U[i] * rd;
    }
    __syncthreads();

    // epilogue: channels c1 = lane, c2 = lane + 64
    const float bias_on = (base < end) ? 1.f : 0.f;
    const int c1 = lane, c2 = lane + 64;

    float agg1 = wvl_b[c1 & 15] * bias_on;
    float agg2 = wvl_b[c2 & 15] * bias_on;
    {
        const float* s1 = &S_lds[wave][(c1 >> 4) * 16];
        const float* s2 = &S_lds[wave][(c2 >> 4) * 16];
        const float* w1 = &wvl_w[(c1 & 15) * 16];
        const float* w2 = &wvl_w[(c2 & 15) * 16];
#pragma unroll
        for (int j = 0; j < 16; j++) {
            agg1 = fmaf(w1[j], s1[j], agg1);
            agg2 = fmaf(w2[j], s2[j], agg2);
        }
    }
    float pre1 = cen_g[(size_t)n * 128 + c1] + agg1;
    float pre2 = cen_g[(size_t)n * 128 + c2] + agg2;
    vl_lds[wave][c1] = ssp(pre1);
    vl_lds[wave][c2] = ssp(pre2);
    __syncthreads();

    float acc1 = out_b[c1], acc2 = out_b[c2];
    {
        const float* vr = vl_lds[wave];
        const float* o1 = out_w + (size_t)c1 * 128;
        const float* o2 = out_w + (size_t)c2 * 128;
#pragma unroll 4
        for (int j = 0; j < 128; j += 4) {
            float4 v = *(const float4*)(vr + j);
            float4 a = ld4(o1 + j);
            float4 b = ld4(o2 + j);
            acc1 = fmaf(v.x, a.x, acc1); acc1 = fmaf(v.y, a.y, acc1);
            acc1 = fmaf(v.z, a.z, acc1); acc1 = fmaf(v.w, a.w, acc1);
            acc2 = fmaf(v.x, b.x, acc2); acc2 = fmaf(v.y, b.y, acc2);
            acc2 = fmaf(v.z, b.z, acc2); acc2 = fmaf(v.w, b.w, acc2);
        }
    }

    // LayerNorm over 128 channels held 2-per-lane
    float s1 = acc1 + acc2;
    float s2 = acc1 * acc1 + acc2 * acc2;
#pragma unroll
    for (int s = 1; s <= 32; s <<= 1) {
        s1 += __shfl_xor(s1, s);
        s2 += __shfl_xor(s2, s);
    }
    float mean = s1 * (1.f / 128.f);
    float var  = s2 * (1.f / 128.f) - mean * mean;
    float inv  = rsqrtf(var + 1e-5f);
    out[(size_t)n * 128 + c1] = (acc1 - mean) * inv * ln_g[c1] + ln_b[c1];
    out[(size_t)n * 128 + c2] = (acc2 - mean) * inv * ln_g[c2] + ln_b[c2];
}

extern "C" void kernel_launch(void* const* d_in, const int* in_sizes, int n_in,
                              void* d_out, int out_size, void* d_ws, size_t ws_size,
                              hipStream_t stream)
{
    (void)in_sizes; (void)n_in; (void)out_size; (void)ws_size;
    const float* node_attr = (const float*)d_in[0];
    const int*   edge_index= (const int*)d_in[1];
    const float* edge_attr = (const float*)d_in[2];
    const float* k_w  = (const float*)d_in[3];
    const float* q_w  = (const float*)d_in[4];
    const float* v_w  = (const float*)d_in[5];
    const float* wk1_w= (const float*)d_in[6];  const float* wk1_b= (const float*)d_in[7];
    const float* wk2_w= (const float*)d_in[8];  const float* wk2_b= (const float*)d_in[9];
    const float* wkl_w= (const float*)d_in[10]; const float* wkl_b= (const float*)d_in[11];
    const float* wv1_w= (const float*)d_in[12]; const float* wv1_b= (const float*)d_in[13];
    const float* wv2_w= (const float*)d_in[14]; const float* wv2_b= (const float*)d_in[15];
    const float* wvl_w= (const float*)d_in[16]; const float* wvl_b= (const float*)d_in[17];
    const float* cen_w= (const float*)d_in[18]; const float* cen_b= (const float*)d_in[19];
    const float* out_w= (const float*)d_in[20]; const float* out_b= (const float*)d_in[21];
    const float* ln_g = (const float*)d_in[22]; const float* ln_b = (const float*)d_in[23];
    float* out = (float*)d_out;

    char* ws = (char*)d_ws;
    size_t o = 0;
    auto alloc = [&](size_t bytes) -> void* {
        void* p = ws + o;
        o += (bytes + 255) & ~(size_t)255;
        return p;
    };
    unsigned int*  hkv_g = (unsigned int*)alloc((size_t)NN * 128 * 4);
    float* qt_g  = (float*)alloc((size_t)NN * 128 * 4);
    float* cen_g = (float*)alloc((size_t)NN * 128 * 4);
    float* qb_g  = (float*)alloc((size_t)NN * 8 * 4);
    unsigned int* wkv_csr = (unsigned int*)alloc((size_t)EE * 16 * 4);
    int* cnt     = (int*)alloc((size_t)NN * 4);
    int* off     = (int*)alloc((size_t)(NN + 1) * 4);
    int* cursor  = (int*)alloc((size_t)NN * 4);
    int* csr_e   = (int*)alloc((size_t)EE * 4);
    int* csr_col = (int*)alloc((size_t)EE * 4);
    short* w1k   = (short*)alloc(1024 * 2);
    short* w1v   = (short*)alloc(1024 * 2);
    short* w2k   = (short*)alloc(256 * 2);
    short* w2v   = (short*)alloc(256 * 2);

    hipMemsetAsync(cnt, 0, (size_t)NN * 4, stream);

    prep_w<<<1, 256, 0, stream>>>(wk1_w, wv1_w, wk2_w, wv2_w, w1k, w1v, w2k, w2v);
    node_pre<<<NN, 128, 0, stream>>>(node_attr, k_w, q_w, v_w, wkl_w, wkl_b,
                                     cen_w, cen_b, hkv_g, qt_g, qb_g, cen_g);
    count_kernel<<<(EE + 255) / 256, 256, 0, stream>>>(edge_index, cnt);
    scan_kernel<<<1, 1024, 0, stream>>>(cnt, off, cursor);
    scatter_kernel<<<(EE + 255) / 256, 256, 0, stream>>>(edge_index, cursor, csr_e, csr_col);
    edge_mlp<<<EE / 64, 256, 0, stream>>>(edge_attr,
                                          w1k, wk1_b, w2k, wk2_b,
                                          w1v, wv1_b, w2v, wv2_b,
                                          csr_e, wkv_csr);
    node_fused<<<NN / 2, 128, 0, stream>>>(off, csr_col, wkv_csr, hkv_g,
                                           qt_g, qb_g, wvl_w, wvl_b, cen_g,
                                           out_w, out_b, ln_g, ln_b, out);
}

// Round 7
// 306.082 us; speedup vs baseline: 2.9862x; 1.8166x over previous
//
#include <hip/hip_runtime.h>
#include <math.h>

#define NN 20000
#define EE 640000
// H=8, Ch=Kh=16, C=K=128, EC=64

typedef __attribute__((ext_vector_type(8))) short short8;
typedef __attribute__((ext_vector_type(4))) float f32x4;

__device__ __forceinline__ float ssp(float x) {
    float sp;
    if (x > 20.f)       sp = x;
    else if (x < -20.f) sp = __expf(x);
    else                sp = log1pf(__expf(x));
    return sp - 0.69314718055994530942f;
}

__device__ __forceinline__ unsigned short f2bf(float f) {
    unsigned u = __float_as_uint(f);
    unsigned r = (u + 0x7FFFu + ((u >> 16) & 1u)) >> 16;
    return (unsigned short)r;
}
__device__ __forceinline__ float bf2f(unsigned short h) {
    return __uint_as_float((unsigned int)h << 16);
}

__device__ __forceinline__ float4 ld4(const float* p) { return *(const float4*)p; }

__device__ __forceinline__ short8 pack8(float4 p, float4 q) {
    short8 r;
    r[0] = (short)f2bf(p.x); r[1] = (short)f2bf(p.y); r[2] = (short)f2bf(p.z); r[3] = (short)f2bf(p.w);
    r[4] = (short)f2bf(q.x); r[5] = (short)f2bf(q.y); r[6] = (short)f2bf(q.z); r[7] = (short)f2bf(q.w);
    return r;
}

// ---------------- one-time weight packing: bf16 (+ hi/lo splits for epilogue GEMMs) ----------------
__global__ __launch_bounds__(256) void prep_w(
    const float* __restrict__ cen_w, const float* __restrict__ out_w,
    const float* __restrict__ wk1_w, const float* __restrict__ wv1_w,
    const float* __restrict__ wk2_w, const float* __restrict__ wv2_w,
    short* __restrict__ cenw_hi, short* __restrict__ cenw_lo,
    short* __restrict__ outw_hi, short* __restrict__ outw_lo,
    short* __restrict__ w1k, short* __restrict__ w1v,
    short* __restrict__ w2k, short* __restrict__ w2v)
{
    const int b = blockIdx.x, t = threadIdx.x;
    if (b < 64) {
        int idx = b * 256 + t;
        float w = cen_w[idx];
        unsigned short hi = f2bf(w);
        cenw_hi[idx] = (short)hi;
        cenw_lo[idx] = (short)f2bf(w - bf2f(hi));
    } else if (b < 128) {
        int idx = (b - 64) * 256 + t;
        float w = out_w[idx];
        unsigned short hi = f2bf(w);
        outw_hi[idx] = (short)hi;
        outw_lo[idx] = (short)f2bf(w - bf2f(hi));
    } else {
        for (int idx = t; idx < 1024; idx += 256) {
            w1k[idx] = (short)f2bf(wk1_w[idx]);
            w1v[idx] = (short)f2bf(wv1_w[idx]);
        }
        w2k[t] = (short)f2bf(wk2_w[t]);
        w2v[t] = (short)f2bf(wv2_w[t]);
    }
}

// ---------------- per-node precompute: hkv (bf16 interleaved), q~, qb ----------------
__global__ __launch_bounds__(128) void node_pre(
    const float* __restrict__ node_attr,
    const float* __restrict__ k_w, const float* __restrict__ q_w, const float* __restrict__ v_w,
    const float* __restrict__ wkl_w, const float* __restrict__ wkl_b,
    unsigned int* __restrict__ hkv_g,
    float* __restrict__ qt_g, float* __restrict__ qb_g)
{
    const int n = blockIdx.x;
    const int t = threadIdx.x;
    __shared__ float x[128];
    __shared__ float hq[128];
    x[t] = node_attr[(size_t)n * 128 + t];
    __syncthreads();
    const int h = t >> 4, i = t & 15;
    const float* xh = &x[h * 16];
    const float* kw = &k_w[h * 256 + i * 16];
    const float* qw = &q_w[h * 256 + i * 16];
    const float* vw = &v_w[h * 256 + i * 16];
    float accK = 0.f, accQ = 0.f, accV = 0.f;
#pragma unroll
    for (int j = 0; j < 16; j++) {
        float xv = xh[j];
        accK = fmaf(xv, kw[j], accK);
        accQ = fmaf(xv, qw[j], accQ);
        accV = fmaf(xv, vw[j], accV);
    }
    hkv_g[(size_t)n * 128 + t] = (unsigned int)f2bf(accK) | ((unsigned int)f2bf(accV) << 16);
    hq[t] = accQ;
    __syncthreads();
    float qt = 0.f;
#pragma unroll
    for (int o = 0; o < 16; o++) qt = fmaf(hq[h * 16 + o], wkl_w[o * 16 + i], qt);
    qt_g[(size_t)n * 128 + t] = 0.25f * qt;
    if (i == 0) {
        float qb = 0.f;
#pragma unroll
        for (int o = 0; o < 16; o++) qb = fmaf(hq[h * 16 + o], wkl_b[o], qb);
        qb_g[(size_t)n * 8 + h] = 0.25f * qb;
    }
}

// ---------------- CSR build ----------------
__global__ void count_kernel(const int* __restrict__ ei, int* __restrict__ cnt) {
    int e = blockIdx.x * 256 + threadIdx.x;
    if (e < EE) atomicAdd(&cnt[ei[e]], 1);
}

__global__ __launch_bounds__(1024) void scan_kernel(const int* __restrict__ cnt,
                                                    int* __restrict__ off, int* __restrict__ cursor) {
    __shared__ int arr[1024];
    const int t = threadIdx.x;
    const int STRIP = 20;
    int start = t * STRIP;
    int end = start + STRIP; if (end > NN) end = NN;
    int local = 0;
    for (int n = start; n < end; n++) local += cnt[n];
    arr[t] = local;
    __syncthreads();
    for (int s = 1; s < 1024; s <<= 1) {
        int v = (t >= s) ? arr[t - s] : 0;
        __syncthreads();
        arr[t] += v;
        __syncthreads();
    }
    int running = arr[t] - local;
    for (int n = start; n < end; n++) {
        off[n] = running;
        cursor[n] = running;
        running += cnt[n];
    }
    if (end == NN) off[NN] = running;
}

__global__ void scatter_kernel(const int* __restrict__ ei, int* __restrict__ cursor,
                               int* __restrict__ csr_e, int* __restrict__ csr_col) {
    int e = blockIdx.x * 256 + threadIdx.x;
    if (e < EE) {
        int p = atomicAdd(&cursor[ei[e]], 1);
        csr_e[p] = e;
        csr_col[p] = ei[EE + e];
    }
}

// ---------------- edge MLP pass (MFMA), CSR order ----------------
__global__ __launch_bounds__(256) void edge_mlp(
    const float* __restrict__ edge_attr,
    const short* __restrict__ w1k, const float* __restrict__ wk1_b,
    const short* __restrict__ w2k, const float* __restrict__ wk2_b,
    const short* __restrict__ w1v, const float* __restrict__ wv1_b,
    const short* __restrict__ w2v, const float* __restrict__ wv2_b,
    const int* __restrict__ csr_e,
    unsigned int* __restrict__ wkv_csr)
{
    __shared__ __align__(16) short lds_k[4][16][16];
    __shared__ __align__(16) short lds_v[4][16][16];

    const int t = threadIdx.x;
    const int wid = t >> 6, lane = t & 63;
    const int row = lane & 15;
    const int kg  = lane >> 4;
    const int e0  = blockIdx.x * 64 + wid * 16;

    const int src = csr_e[e0 + row];
    const float* ea = edge_attr + (size_t)src * 64 + kg * 8;
    short8 A0 = pack8(ld4(ea),      ld4(ea + 4));
    short8 A1 = pack8(ld4(ea + 32), ld4(ea + 36));

    short8 BK0 = *(const short8*)(w1k + row * 64 + kg * 8);
    short8 BK1 = *(const short8*)(w1k + row * 64 + kg * 8 + 32);
    short8 BV0 = *(const short8*)(w1v + row * 64 + kg * 8);
    short8 BV1 = *(const short8*)(w1v + row * 64 + kg * 8 + 32);

    float bk = wk1_b[row], bv = wv1_b[row];
    f32x4 ck = {bk, bk, bk, bk};
    f32x4 cv = {bv, bv, bv, bv};
    ck = __builtin_amdgcn_mfma_f32_16x16x32_bf16(A0, BK0, ck, 0, 0, 0);
    ck = __builtin_amdgcn_mfma_f32_16x16x32_bf16(A1, BK1, ck, 0, 0, 0);
    cv = __builtin_amdgcn_mfma_f32_16x16x32_bf16(A0, BV0, cv, 0, 0, 0);
    cv = __builtin_amdgcn_mfma_f32_16x16x32_bf16(A1, BV1, cv, 0, 0, 0);

#pragma unroll
    for (int r = 0; r < 4; r++) {
        lds_k[wid][kg * 4 + r][row] = (short)f2bf(ssp(ck[r]));
        lds_v[wid][kg * 4 + r][row] = (short)f2bf(ssp(cv[r]));
    }
    __syncthreads();

    short8 A2K = (short8)0, A2V = (short8)0, B2K = (short8)0, B2V = (short8)0;
    if (kg < 2) {
        A2K = *(const short8*)&lds_k[wid][row][kg * 8];
        A2V = *(const short8*)&lds_v[wid][row][kg * 8];
        B2K = *(const short8*)(w2k + row * 16 + kg * 8);
        B2V = *(const short8*)(w2v + row * 16 + kg * 8);
    }
    float b2k = wk2_b[row], b2v = wv2_b[row];
    f32x4 c2k = {b2k, b2k, b2k, b2k};
    f32x4 c2v = {b2v, b2v, b2v, b2v};
    c2k = __builtin_amdgcn_mfma_f32_16x16x32_bf16(A2K, B2K, c2k, 0, 0, 0);
    c2v = __builtin_amdgcn_mfma_f32_16x16x32_bf16(A2V, B2V, c2v, 0, 0, 0);

#pragma unroll
    for (int r = 0; r < 4; r++) {
        int el = kg * 4 + r;
        wkv_csr[(size_t)(e0 + el) * 16 + row] =
            (unsigned int)f2bf(c2k[r]) | ((unsigned int)f2bf(c2v[r]) << 16);
    }
}

// ---------------- attention: 1 wave/node, 2 lanes per (edge,head), 8 ch/lane ----------------
__device__ __forceinline__ void edge_step(
    uint4 k0, uint4 k1, uint4 w0, uint4 w1,
    const float* qt, float qbh, bool valid,
    float* U, float& d)
{
    unsigned int kk[8] = {k0.x, k0.y, k0.z, k0.w, k1.x, k1.y, k1.z, k1.w};
    unsigned int ww[8] = {w0.x, w0.y, w0.z, w0.w, w1.x, w1.y, w1.z, w1.w};
    float term = 0.f;
    float uv[8];
#pragma unroll
    for (int i = 0; i < 8; i++) {
        float hk = __uint_as_float(kk[i] << 16);
        float hv = __uint_as_float(kk[i] & 0xFFFF0000u);
        float wk = __uint_as_float(ww[i] << 16);
        float wv = __uint_as_float(ww[i] & 0xFFFF0000u);
        term = fmaf(wk * hk, qt[i], term);
        uv[i] = wv * hv;
    }
    term += __shfl_xor(term, 1);   // combine the two channel-halves
    float ex = __expf(term + qbh);
    ex = valid ? ex : 0.f;
    d += ex;
#pragma unroll
    for (int i = 0; i < 8; i++) U[i] = fmaf(ex, uv[i], U[i]);
}

__global__ __launch_bounds__(256) void node_attn(
    const int* __restrict__ off, const int* __restrict__ csr_col,
    const unsigned int* __restrict__ wkv_csr,
    const unsigned int* __restrict__ hkv_g,
    const float* __restrict__ qt_g, const float* __restrict__ qb_g,
    unsigned short* __restrict__ S_g16)
{
    const int wave = threadIdx.x >> 6;
    const int lane = threadIdx.x & 63;
    const int n = blockIdx.x * 4 + wave;
    const int half  = lane & 1;        // channel half (0..7 / 8..15)
    const int h     = (lane >> 1) & 7; // head
    const int eslot = lane >> 4;       // 0..3

    const int base = off[n], end = off[n + 1];
    const int coff = h * 16 + half * 8;

    float qt[8];
    {
        const float* q = qt_g + (size_t)n * 128 + coff;
        *(float4*)(qt + 0) = ld4(q + 0);
        *(float4*)(qt + 4) = ld4(q + 4);
    }
    const float qbh = qb_g[(size_t)n * 8 + h];

    float U[8];
#pragma unroll
    for (int i = 0; i < 8; i++) U[i] = 0.f;
    float d = 0.f;

    for (int j0 = base; j0 < end; j0 += 8) {
        const int jA = j0 + eslot;
        const int jB = j0 + 4 + eslot;
        const bool vA = jA < end, vB = jB < end;
        const int jjA = vA ? jA : base;
        const int jjB = vB ? jB : base;
        const int clA = csr_col[jjA];
        const int clB = csr_col[jjB];

        const unsigned int* kpA = hkv_g + (size_t)clA * 128 + coff;
        const unsigned int* wpA = wkv_csr + (size_t)jjA * 16 + half * 8;
        const unsigned int* kpB = hkv_g + (size_t)clB * 128 + coff;
        const unsigned int* wpB = wkv_csr + (size_t)jjB * 16 + half * 8;
        uint4 ka0 = *(const uint4*)(kpA), ka1 = *(const uint4*)(kpA + 4);
        uint4 wa0 = *(const uint4*)(wpA), wa1 = *(const uint4*)(wpA + 4);
        uint4 kb0 = *(const uint4*)(kpB), kb1 = *(const uint4*)(kpB + 4);
        uint4 wb0 = *(const uint4*)(wpB), wb1 = *(const uint4*)(wpB + 4);

        edge_step(ka0, ka1, wa0, wa1, qt, qbh, vA, U, d);
        edge_step(kb0, kb1, wb0, wb1, qt, qbh, vB, U, d);
    }

    // reduce across the 4 edge slots
#pragma unroll
    for (int s = 16; s <= 32; s <<= 1) {
        d += __shfl_xor(d, s);
#pragma unroll
        for (int i = 0; i < 8; i++) U[i] += __shfl_xor(U[i], s);
    }

    if (lane < 16) {
        const float rd = (end > base) ? (1.f / d) : 0.f;
        short8 o;
#pragma unroll
        for (int i = 0; i < 8; i++) o[i] = (short)f2bf(U[i] * rd);
        *(short8*)(S_g16 + (size_t)n * 128 + coff) = o;
    }
}

// ---------------- epilogue: wvl fold + cen GEMM + ssp + out GEMM + LN (MFMA, 32 nodes/block) ----------------
__global__ __launch_bounds__(256) void node_out(
    const int* __restrict__ off,
    const unsigned short* __restrict__ S_g16,
    const float* __restrict__ node_attr,
    const short* __restrict__ cenw_hi, const short* __restrict__ cenw_lo, const float* __restrict__ cen_b,
    const short* __restrict__ outw_hi, const short* __restrict__ outw_lo, const float* __restrict__ out_b,
    const float* __restrict__ wvl_w, const float* __restrict__ wvl_b,
    const float* __restrict__ ln_g, const float* __restrict__ ln_b,
    float* __restrict__ out)
{
    __shared__ float S_lds[32][132];    // S tile; later reused as out tile
    __shared__ float agg_lds[32][132];
    __shared__ __align__(16) short vlh_lds[32][136];  // na_hi, then vl_hi
    __shared__ __align__(16) short vll_lds[32][136];  // na_lo, then vl_lo
    __shared__ float wvl_lds[256];

    const int tid = threadIdx.x;
    const int w   = tid >> 6;
    const int lane = tid & 63;
    const int col = lane & 15, kg = lane >> 4;
    const int n0 = blockIdx.x * 32;
    const int mt = w & 1;              // M-tile (16 nodes)
    const int ntb = (w >> 1) * 4;      // N-tiles ntb..ntb+3

    // stage S (bf16->f32) and node_attr (f32 -> hi/lo bf16 in the vl buffers)
    for (int idx = tid; idx < 32 * 128; idx += 256) {
        int r = idx >> 7, c = idx & 127;
        S_lds[r][c] = bf2f(S_g16[(size_t)(n0 + r) * 128 + c]);
        float v = node_attr[(size_t)(n0 + r) * 128 + c];
        unsigned short hi = f2bf(v);
        vlh_lds[r][c] = (short)hi;
        vll_lds[r][c] = (short)f2bf(v - bf2f(hi));
    }
    wvl_lds[tid] = wvl_w[tid];
    __syncthreads();

    // GEMM1: cen = na @ cen_w^T + cen_b  (bf16 hi/lo, 3-term split), A from LDS
    f32x4 C1[4];
#pragma unroll
    for (int nt = 0; nt < 4; nt++) {
        float cb = cen_b[(ntb + nt) * 16 + col];
        C1[nt] = (f32x4){cb, cb, cb, cb};
    }
    {
        const int arow = mt * 16 + col;
#pragma unroll
        for (int ks = 0; ks < 4; ks++) {
            const int k0 = ks * 32 + kg * 8;
            short8 Ah = *(const short8*)&vlh_lds[arow][k0];
            short8 Al = *(const short8*)&vll_lds[arow][k0];
#pragma unroll
            for (int nt = 0; nt < 4; nt++) {
                const int brow = ((ntb + nt) * 16 + col) * 128 + k0;
                short8 Bh = *(const short8*)(cenw_hi + brow);
                short8 Bl = *(const short8*)(cenw_lo + brow);
                C1[nt] = __builtin_amdgcn_mfma_f32_16x16x32_bf16(Ah, Bh, C1[nt], 0, 0, 0);
                C1[nt] = __builtin_amdgcn_mfma_f32_16x16x32_bf16(Al, Bh, C1[nt], 0, 0, 0);
                C1[nt] = __builtin_amdgcn_mfma_f32_16x16x32_bf16(Ah, Bl, C1[nt], 0, 0, 0);
            }
        }
    }

    // P2: agg = wvl . S (+ wvl_b if node has edges)
    {
        const int r = tid >> 3;
        const int hh = tid & 7;          // head
        const int og = hh * 16;
        float sseg[16];
#pragma unroll
        for (int q = 0; q < 4; q++) {
            float4 v = *(const float4*)&S_lds[r][og + q * 4];
            sseg[q * 4 + 0] = v.x; sseg[q * 4 + 1] = v.y;
            sseg[q * 4 + 2] = v.z; sseg[q * 4 + 3] = v.w;
        }
        const float flag = (off[n0 + r + 1] > off[n0 + r]) ? 1.f : 0.f;
#pragma unroll
        for (int oo = 0; oo < 16; oo++) {
            float acc = wvl_b[oo] * flag;
            const float* wr = &wvl_lds[oo * 16];
#pragma unroll
            for (int jj = 0; jj < 16; jj++) acc = fmaf(wr[jj], sseg[jj], acc);
            agg_lds[r][og + oo] = acc;
        }
    }
    __syncthreads();

    // P3: vl = ssp(cen + agg) -> hi/lo bf16 in LDS (overwrites the na staging)
#pragma unroll
    for (int nt = 0; nt < 4; nt++) {
        const int c = (ntb + nt) * 16 + col;
#pragma unroll
        for (int r_ = 0; r_ < 4; r_++) {
            const int rr = mt * 16 + kg * 4 + r_;
            float v = ssp(C1[nt][r_] + agg_lds[rr][c]);
            unsigned short hi = f2bf(v);
            vlh_lds[rr][c] = (short)hi;
            vll_lds[rr][c] = (short)f2bf(v - bf2f(hi));
        }
    }
    __syncthreads();

    // P4: out = vl @ out_w^T + out_b  (bf16 hi/lo, 3-term)
    f32x4 C2[4];
#pragma unroll
    for (int nt = 0; nt < 4; nt++) {
        float ob = out_b[(ntb + nt) * 16 + col];
        C2[nt] = (f32x4){ob, ob, ob, ob};
    }
    {
        const int arow = mt * 16 + col;
#pragma unroll
        for (int ks = 0; ks < 4; ks++) {
            const int k0 = ks * 32 + kg * 8;
            short8 Ah = *(const short8*)&vlh_lds[arow][k0];
            short8 Al = *(const short8*)&vll_lds[arow][k0];
#pragma unroll
            for (int nt = 0; nt < 4; nt++) {
                const int brow = ((ntb + nt) * 16 + col) * 128 + k0;
                short8 Bh = *(const short8*)(outw_hi + brow);
                short8 Bl = *(const short8*)(outw_lo + brow);
                C2[nt] = __builtin_amdgcn_mfma_f32_16x16x32_bf16(Ah, Bh, C2[nt], 0, 0, 0);
                C2[nt] = __builtin_amdgcn_mfma_f32_16x16x32_bf16(Al, Bh, C2[nt], 0, 0, 0);
                C2[nt] = __builtin_amdgcn_mfma_f32_16x16x32_bf16(Ah, Bl, C2[nt], 0, 0, 0);
            }
        }
    }
    // write out tile (reuse S_lds)
#pragma unroll
    for (int nt = 0; nt < 4; nt++) {
        const int c = (ntb + nt) * 16 + col;
#pragma unroll
        for (int r_ = 0; r_ < 4; r_++) {
            S_lds[mt * 16 + kg * 4 + r_][c] = C2[nt][r_];
        }
    }
    __syncthreads();

    // P5: LayerNorm per node row + store
    {
        const int r = tid >> 3;
        const int g = tid & 7;
        float vals[16];
#pragma unroll
        for (int q = 0; q < 4; q++) {
            float4 v = *(const float4*)&S_lds[r][g * 16 + q * 4];
            vals[q * 4 + 0] = v.x; vals[q * 4 + 1] = v.y;
            vals[q * 4 + 2] = v.z; vals[q * 4 + 3] = v.w;
        }
        float s1 = 0.f, s2 = 0.f;
#pragma unroll
        for (int q = 0; q < 16; q++) { s1 += vals[q]; s2 = fmaf(vals[q], vals[q], s2); }
#pragma unroll
        for (int s = 1; s <= 4; s <<= 1) {
            s1 += __shfl_xor(s1, s);
            s2 += __shfl_xor(s2, s);
        }
        const float mean = s1 * (1.f / 128.f);
        const float var  = s2 * (1.f / 128.f) - mean * mean;
        const float inv  = rsqrtf(var + 1e-5f);
        float o[16];
#pragma unroll
        for (int q = 0; q < 16; q++) {
            const int c = g * 16 + q;
            o[q] = (vals[q] - mean) * inv * ln_g[c] + ln_b[c];
        }
        float* op = out + (size_t)(n0 + r) * 128 + g * 16;
#pragma unroll
        for (int q = 0; q < 4; q++) *(float4*)(op + q * 4) = *(float4*)(o + q * 4);
    }
}

extern "C" void kernel_launch(void* const* d_in, const int* in_sizes, int n_in,
                              void* d_out, int out_size, void* d_ws, size_t ws_size,
                              hipStream_t stream)
{
    (void)in_sizes; (void)n_in; (void)out_size; (void)ws_size;
    const float* node_attr = (const float*)d_in[0];
    const int*   edge_index= (const int*)d_in[1];
    const float* edge_attr = (const float*)d_in[2];
    const float* k_w  = (const float*)d_in[3];
    const float* q_w  = (const float*)d_in[4];
    const float* v_w  = (const float*)d_in[5];
    const float* wk1_w= (const float*)d_in[6];  const float* wk1_b= (const float*)d_in[7];
    const float* wk2_w= (const float*)d_in[8];  const float* wk2_b= (const float*)d_in[9];
    const float* wkl_w= (const float*)d_in[10]; const float* wkl_b= (const float*)d_in[11];
    const float* wv1_w= (const float*)d_in[12]; const float* wv1_b= (const float*)d_in[13];
    const float* wv2_w= (const float*)d_in[14]; const float* wv2_b= (const float*)d_in[15];
    const float* wvl_w= (const float*)d_in[16]; const float* wvl_b= (const float*)d_in[17];
    const float* cen_w= (const float*)d_in[18]; const float* cen_b= (const float*)d_in[19];
    const float* out_w= (const float*)d_in[20]; const float* out_b= (const float*)d_in[21];
    const float* ln_g = (const float*)d_in[22]; const float* ln_b = (const float*)d_in[23];
    float* out = (float*)d_out;

    char* ws = (char*)d_ws;
    size_t o = 0;
    auto alloc = [&](size_t bytes) -> void* {
        void* p = ws + o;
        o += (bytes + 255) & ~(size_t)255;
        return p;
    };
    unsigned int* hkv_g = (unsigned int*)alloc((size_t)NN * 128 * 4);
    float* qt_g  = (float*)alloc((size_t)NN * 128 * 4);
    float* qb_g  = (float*)alloc((size_t)NN * 8 * 4);
    unsigned short* S_g16 = (unsigned short*)alloc((size_t)NN * 128 * 2);
    unsigned int* wkv_csr = (unsigned int*)alloc((size_t)EE * 16 * 4);
    int* cnt     = (int*)alloc((size_t)NN * 4);
    int* off     = (int*)alloc((size_t)(NN + 1) * 4);
    int* cursor  = (int*)alloc((size_t)NN * 4);
    int* csr_e   = (int*)alloc((size_t)EE * 4);
    int* csr_col = (int*)alloc((size_t)EE * 4);
    short* cenw_hi = (short*)alloc(16384 * 2);
    short* cenw_lo = (short*)alloc(16384 * 2);
    short* outw_hi = (short*)alloc(16384 * 2);
    short* outw_lo = (short*)alloc(16384 * 2);
    short* w1k   = (short*)alloc(1024 * 2);
    short* w1v   = (short*)alloc(1024 * 2);
    short* w2k   = (short*)alloc(256 * 2);
    short* w2v   = (short*)alloc(256 * 2);

    hipMemsetAsync(cnt, 0, (size_t)NN * 4, stream);

    prep_w<<<129, 256, 0, stream>>>(cen_w, out_w, wk1_w, wv1_w, wk2_w, wv2_w,
                                    cenw_hi, cenw_lo, outw_hi, outw_lo,
                                    w1k, w1v, w2k, w2v);
    node_pre<<<NN, 128, 0, stream>>>(node_attr, k_w, q_w, v_w, wkl_w, wkl_b,
                                     hkv_g, qt_g, qb_g);
    count_kernel<<<(EE + 255) / 256, 256, 0, stream>>>(edge_index, cnt);
    scan_kernel<<<1, 1024, 0, stream>>>(cnt, off, cursor);
    scatter_kernel<<<(EE + 255) / 256, 256, 0, stream>>>(edge_index, cursor, csr_e, csr_col);
    edge_mlp<<<EE / 64, 256, 0, stream>>>(edge_attr,
                                          w1k, wk1_b, w2k, wk2_b,
                                          w1v, wv1_b, w2v, wv2_b,
                                          csr_e, wkv_csr);
    node_attn<<<NN / 4, 256, 0, stream>>>(off, csr_col, wkv_csr, hkv_g,
                                          qt_g, qb_g, S_g16);
    node_out<<<NN / 32, 256, 0, stream>>>(off, S_g16, node_attr,
                                          cenw_hi, cenw_lo, cen_b,
                                          outw_hi, outw_lo, out_b,
                                          wvl_w, wvl_b, ln_g, ln_b, out);
}

// Round 11
// 302.334 us; speedup vs baseline: 3.0232x; 1.0124x over previous
//
#include <hip/hip_runtime.h>
#include <math.h>

#define NN 20000
#define EE 640000
// H=8, Ch=Kh=16, C=K=128, EC=64

typedef __attribute__((ext_vector_type(8))) short short8;
typedef __attribute__((ext_vector_type(4))) float f32x4;

// PROVEN ssp (R7). NOTE: node_pre 16-nodes/block restructure correlates with
// absmax 0.067->0.133 (R8/R9/R10, root cause unidentified) — do not reapply.
__device__ __forceinline__ float ssp(float x) {
    float sp;
    if (x > 20.f)       sp = x;
    else if (x < -20.f) sp = __expf(x);
    else                sp = log1pf(__expf(x));
    return sp - 0.69314718055994530942f;
}

__device__ __forceinline__ unsigned short f2bf(float f) {
    unsigned u = __float_as_uint(f);
    unsigned r = (u + 0x7FFFu + ((u >> 16) & 1u)) >> 16;
    return (unsigned short)r;
}
__device__ __forceinline__ float bf2f(unsigned short h) {
    return __uint_as_float((unsigned int)h << 16);
}

__device__ __forceinline__ float4 ld4(const float* p) { return *(const float4*)p; }

__device__ __forceinline__ short8 pack8(float4 p, float4 q) {
    short8 r;
    r[0] = (short)f2bf(p.x); r[1] = (short)f2bf(p.y); r[2] = (short)f2bf(p.z); r[3] = (short)f2bf(p.w);
    r[4] = (short)f2bf(q.x); r[5] = (short)f2bf(q.y); r[6] = (short)f2bf(q.z); r[7] = (short)f2bf(q.w);
    return r;
}

// ---------------- one-time weight packing ----------------
__global__ __launch_bounds__(256) void prep_w(
    const float* __restrict__ cen_w, const float* __restrict__ out_w,
    const float* __restrict__ wk1_w, const float* __restrict__ wv1_w,
    const float* __restrict__ wk2_w, const float* __restrict__ wv2_w,
    short* __restrict__ cenw_hi, short* __restrict__ cenw_lo,
    short* __restrict__ outw_hi, short* __restrict__ outw_lo,
    short* __restrict__ w1k, short* __restrict__ w1v,
    short* __restrict__ w2k, short* __restrict__ w2v)
{
    const int b = blockIdx.x, t = threadIdx.x;
    if (b < 64) {
        int idx = b * 256 + t;
        float w = cen_w[idx];
        unsigned short hi = f2bf(w);
        cenw_hi[idx] = (short)hi;
        cenw_lo[idx] = (short)f2bf(w - bf2f(hi));
    } else if (b < 128) {
        int idx = (b - 64) * 256 + t;
        float w = out_w[idx];
        unsigned short hi = f2bf(w);
        outw_hi[idx] = (short)hi;
        outw_lo[idx] = (short)f2bf(w - bf2f(hi));
    } else {
        for (int idx = t; idx < 1024; idx += 256) {
            w1k[idx] = (short)f2bf(wk1_w[idx]);
            w1v[idx] = (short)f2bf(wv1_w[idx]);
        }
        w2k[t] = (short)f2bf(wk2_w[t]);
        w2v[t] = (short)f2bf(wv2_w[t]);
    }
}

// ---------------- per-node precompute (EXACT R7: one node per block) ----------------
__global__ __launch_bounds__(128) void node_pre(
    const float* __restrict__ node_attr,
    const float* __restrict__ k_w, const float* __restrict__ q_w, const float* __restrict__ v_w,
    const float* __restrict__ wkl_w, const float* __restrict__ wkl_b,
    unsigned int* __restrict__ hkv_g,
    float* __restrict__ qt_g, float* __restrict__ qb_g)
{
    const int n = blockIdx.x;
    const int t = threadIdx.x;
    __shared__ float x[128];
    __shared__ float hq[128];
    x[t] = node_attr[(size_t)n * 128 + t];
    __syncthreads();
    const int h = t >> 4, i = t & 15;
    const float* xh = &x[h * 16];
    const float* kw = &k_w[h * 256 + i * 16];
    const float* qw = &q_w[h * 256 + i * 16];
    const float* vw = &v_w[h * 256 + i * 16];
    float accK = 0.f, accQ = 0.f, accV = 0.f;
#pragma unroll
    for (int j = 0; j < 16; j++) {
        float xv = xh[j];
        accK = fmaf(xv, kw[j], accK);
        accQ = fmaf(xv, qw[j], accQ);
        accV = fmaf(xv, vw[j], accV);
    }
    hkv_g[(size_t)n * 128 + t] = (unsigned int)f2bf(accK) | ((unsigned int)f2bf(accV) << 16);
    hq[t] = accQ;
    __syncthreads();
    float qt = 0.f;
#pragma unroll
    for (int o = 0; o < 16; o++) qt = fmaf(hq[h * 16 + o], wkl_w[o * 16 + i], qt);
    qt_g[(size_t)n * 128 + t] = 0.25f * qt;
    if (i == 0) {
        float qb = 0.f;
#pragma unroll
        for (int o = 0; o < 16; o++) qb = fmaf(hq[h * 16 + o], wkl_b[o], qb);
        qb_g[(size_t)n * 8 + h] = 0.25f * qb;
    }
}

// ---------------- CSR build ----------------
__global__ void count_kernel(const int* __restrict__ ei, int* __restrict__ cnt) {
    int e = blockIdx.x * 256 + threadIdx.x;
    if (e < EE) atomicAdd(&cnt[ei[e]], 1);
}

__global__ __launch_bounds__(1024) void scan_kernel(const int* __restrict__ cnt,
                                                    int* __restrict__ off, int* __restrict__ cursor) {
    __shared__ int arr[1024];
    const int t = threadIdx.x;
    const int STRIP = 20;
    int start = t * STRIP;
    int end = start + STRIP; if (end > NN) end = NN;
    int local = 0;
    for (int n = start; n < end; n++) local += cnt[n];
    arr[t] = local;
    __syncthreads();
    for (int s = 1; s < 1024; s <<= 1) {
        int v = (t >= s) ? arr[t - s] : 0;
        __syncthreads();
        arr[t] += v;
        __syncthreads();
    }
    int running = arr[t] - local;
    for (int n = start; n < end; n++) {
        off[n] = running;
        cursor[n] = running;
        running += cnt[n];
    }
    if (end == NN) off[NN] = running;
}

__global__ void scatter_kernel(const int* __restrict__ ei, int* __restrict__ cursor,
                               int* __restrict__ csr_e, int* __restrict__ csr_col) {
    int e = blockIdx.x * 256 + threadIdx.x;
    if (e < EE) {
        int p = atomicAdd(&cursor[ei[e]], 1);
        csr_e[p] = e;
        csr_col[p] = ei[EE + e];
    }
}

// ---------------- edge MLP pass (MFMA), CSR order ----------------
__global__ __launch_bounds__(256) void edge_mlp(
    const float* __restrict__ edge_attr,
    const short* __restrict__ w1k, const float* __restrict__ wk1_b,
    const short* __restrict__ w2k, const float* __restrict__ wk2_b,
    const short* __restrict__ w1v, const float* __restrict__ wv1_b,
    const short* __restrict__ w2v, const float* __restrict__ wv2_b,
    const int* __restrict__ csr_e,
    unsigned int* __restrict__ wkv_csr)
{
    __shared__ __align__(16) short lds_k[4][16][16];
    __shared__ __align__(16) short lds_v[4][16][16];

    const int t = threadIdx.x;
    const int wid = t >> 6, lane = t & 63;
    const int row = lane & 15;
    const int kg  = lane >> 4;
    const int e0  = blockIdx.x * 64 + wid * 16;

    const int src = csr_e[e0 + row];
    const float* ea = edge_attr + (size_t)src * 64 + kg * 8;
    short8 A0 = pack8(ld4(ea),      ld4(ea + 4));
    short8 A1 = pack8(ld4(ea + 32), ld4(ea + 36));

    short8 BK0 = *(const short8*)(w1k + row * 64 + kg * 8);
    short8 BK1 = *(const short8*)(w1k + row * 64 + kg * 8 + 32);
    short8 BV0 = *(const short8*)(w1v + row * 64 + kg * 8);
    short8 BV1 = *(const short8*)(w1v + row * 64 + kg * 8 + 32);

    float bk = wk1_b[row], bv = wv1_b[row];
    f32x4 ck = {bk, bk, bk, bk};
    f32x4 cv = {bv, bv, bv, bv};
    ck = __builtin_amdgcn_mfma_f32_16x16x32_bf16(A0, BK0, ck, 0, 0, 0);
    ck = __builtin_amdgcn_mfma_f32_16x16x32_bf16(A1, BK1, ck, 0, 0, 0);
    cv = __builtin_amdgcn_mfma_f32_16x16x32_bf16(A0, BV0, cv, 0, 0, 0);
    cv = __builtin_amdgcn_mfma_f32_16x16x32_bf16(A1, BV1, cv, 0, 0, 0);

#pragma unroll
    for (int r = 0; r < 4; r++) {
        lds_k[wid][kg * 4 + r][row] = (short)f2bf(ssp(ck[r]));
        lds_v[wid][kg * 4 + r][row] = (short)f2bf(ssp(cv[r]));
    }
    __syncthreads();

    short8 A2K = (short8)0, A2V = (short8)0, B2K = (short8)0, B2V = (short8)0;
    if (kg < 2) {
        A2K = *(const short8*)&lds_k[wid][row][kg * 8];
        A2V = *(const short8*)&lds_v[wid][row][kg * 8];
        B2K = *(const short8*)(w2k + row * 16 + kg * 8);
        B2V = *(const short8*)(w2v + row * 16 + kg * 8);
    }
    float b2k = wk2_b[row], b2v = wv2_b[row];
    f32x4 c2k = {b2k, b2k, b2k, b2k};
    f32x4 c2v = {b2v, b2v, b2v, b2v};
    c2k = __builtin_amdgcn_mfma_f32_16x16x32_bf16(A2K, B2K, c2k, 0, 0, 0);
    c2v = __builtin_amdgcn_mfma_f32_16x16x32_bf16(A2V, B2V, c2v, 0, 0, 0);

#pragma unroll
    for (int r = 0; r < 4; r++) {
        int el = kg * 4 + r;
        wkv_csr[(size_t)(e0 + el) * 16 + row] =
            (unsigned int)f2bf(c2k[r]) | ((unsigned int)f2bf(c2v[r]) << 16);
    }
}

// ---------------- attention: software-pipelined gathers (bit-identical accumulation) ----------------
__device__ __forceinline__ void edge_step(
    uint4 k0, uint4 k1, uint4 w0, uint4 w1,
    const float* qt, float qbh, bool valid,
    float* U, float& d)
{
    unsigned int kk[8] = {k0.x, k0.y, k0.z, k0.w, k1.x, k1.y, k1.z, k1.w};
    unsigned int ww[8] = {w0.x, w0.y, w0.z, w0.w, w1.x, w1.y, w1.z, w1.w};
    float term = 0.f;
    float uv[8];
#pragma unroll
    for (int i = 0; i < 8; i++) {
        float hk = __uint_as_float(kk[i] << 16);
        float hv = __uint_as_float(kk[i] & 0xFFFF0000u);
        float wk = __uint_as_float(ww[i] << 16);
        float wv = __uint_as_float(ww[i] & 0xFFFF0000u);
        term = fmaf(wk * hk, qt[i], term);
        uv[i] = wv * hv;
    }
    term += __shfl_xor(term, 1);
    float ex = __expf(term + qbh);
    ex = valid ? ex : 0.f;
    d += ex;
#pragma unroll
    for (int i = 0; i < 8; i++) U[i] = fmaf(ex, uv[i], U[i]);
}

#define LOAD_EDGES(J0, KA0,KA1,WA0,WA1,KB0,KB1,WB0,WB1, VA,VB) do {          \
    int jA_ = (J0) + eslot, jB_ = (J0) + 4 + eslot;                          \
    VA = jA_ < end; VB = jB_ < end;                                          \
    int jjA_ = VA ? jA_ : base, jjB_ = VB ? jB_ : base;                      \
    int clA_ = csr_col[jjA_], clB_ = csr_col[jjB_];                          \
    const unsigned int* kpA_ = hkv_g + (size_t)clA_ * 128 + coff;            \
    const unsigned int* wpA_ = wkv_csr + (size_t)jjA_ * 16 + half * 8;       \
    const unsigned int* kpB_ = hkv_g + (size_t)clB_ * 128 + coff;            \
    const unsigned int* wpB_ = wkv_csr + (size_t)jjB_ * 16 + half * 8;       \
    KA0 = *(const uint4*)(kpA_); KA1 = *(const uint4*)(kpA_ + 4);            \
    WA0 = *(const uint4*)(wpA_); WA1 = *(const uint4*)(wpA_ + 4);            \
    KB0 = *(const uint4*)(kpB_); KB1 = *(const uint4*)(kpB_ + 4);            \
    WB0 = *(const uint4*)(wpB_); WB1 = *(const uint4*)(wpB_ + 4);            \
} while (0)

__global__ __launch_bounds__(256) void node_attn(
    const int* __restrict__ off, const int* __restrict__ csr_col,
    const unsigned int* __restrict__ wkv_csr,
    const unsigned int* __restrict__ hkv_g,
    const float* __restrict__ qt_g, const float* __restrict__ qb_g,
    unsigned short* __restrict__ S_g16)
{
    const int wave = threadIdx.x >> 6;
    const int lane = threadIdx.x & 63;
    const int n = blockIdx.x * 4 + wave;
    const int half  = lane & 1;
    const int h     = (lane >> 1) & 7;
    const int eslot = lane >> 4;

    const int base = off[n], end = off[n + 1];
    const int coff = h * 16 + half * 8;

    float qt[8];
    {
        const float* q = qt_g + (size_t)n * 128 + coff;
        *(float4*)(qt + 0) = ld4(q + 0);
        *(float4*)(qt + 4) = ld4(q + 4);
    }
    const float qbh = qb_g[(size_t)n * 8 + h];

    float U[8];
#pragma unroll
    for (int i = 0; i < 8; i++) U[i] = 0.f;
    float d = 0.f;

    if (base < end) {
        uint4 ka0, ka1, wa0, wa1, kb0, kb1, wb0, wb1;
        bool vA, vB;
        LOAD_EDGES(base, ka0, ka1, wa0, wa1, kb0, kb1, wb0, wb1, vA, vB);
        for (int j0 = base; j0 < end; j0 += 8) {
            uint4 nka0, nka1, nwa0, nwa1, nkb0, nkb1, nwb0, nwb1;
            bool nvA = false, nvB = false;
            const int nj = j0 + 8;
            if (nj < end)
                LOAD_EDGES(nj, nka0, nka1, nwa0, nwa1, nkb0, nkb1, nwb0, nwb1, nvA, nvB);
            // consume current (same order as R7: A then B, ascending j0 -> bit-identical)
            edge_step(ka0, ka1, wa0, wa1, qt, qbh, vA, U, d);
            edge_step(kb0, kb1, wb0, wb1, qt, qbh, vB, U, d);
            if (nj < end) {
                ka0 = nka0; ka1 = nka1; wa0 = nwa0; wa1 = nwa1;
                kb0 = nkb0; kb1 = nkb1; wb0 = nwb0; wb1 = nwb1;
                vA = nvA; vB = nvB;
            }
        }
    }

#pragma unroll
    for (int s = 16; s <= 32; s <<= 1) {
        d += __shfl_xor(d, s);
#pragma unroll
        for (int i = 0; i < 8; i++) U[i] += __shfl_xor(U[i], s);
    }

    if (lane < 16) {
        const float rd = (end > base) ? (1.f / d) : 0.f;
        short8 o;
#pragma unroll
        for (int i = 0; i < 8; i++) o[i] = (short)f2bf(U[i] * rd);
        *(short8*)(S_g16 + (size_t)n * 128 + coff) = o;
    }
}

// ---------------- epilogue: wvl fold + cen GEMM + ssp + out GEMM + LN ----------------
__global__ __launch_bounds__(256) void node_out(
    const int* __restrict__ off,
    const unsigned short* __restrict__ S_g16,
    const float* __restrict__ node_attr,
    const short* __restrict__ cenw_hi, const short* __restrict__ cenw_lo, const float* __restrict__ cen_b,
    const short* __restrict__ outw_hi, const short* __restrict__ outw_lo, const float* __restrict__ out_b,
    const float* __restrict__ wvl_w, const float* __restrict__ wvl_b,
    const float* __restrict__ ln_g, const float* __restrict__ ln_b,
    float* __restrict__ out)
{
    __shared__ float S_lds[32][132];
    __shared__ float agg_lds[32][132];
    __shared__ __align__(16) short vlh_lds[32][136];
    __shared__ __align__(16) short vll_lds[32][136];
    __shared__ float wvl_lds[256];

    const int tid = threadIdx.x;
    const int w   = tid >> 6;
    const int lane = tid & 63;
    const int col = lane & 15, kg = lane >> 4;
    const int n0 = blockIdx.x * 32;
    const int mt = w & 1;
    const int ntb = (w >> 1) * 4;

    for (int idx = tid; idx < 32 * 128; idx += 256) {
        int r = idx >> 7, c = idx & 127;
        S_lds[r][c] = bf2f(S_g16[(size_t)(n0 + r) * 128 + c]);
        float v = node_attr[(size_t)(n0 + r) * 128 + c];
        unsigned short hi = f2bf(v);
        vlh_lds[r][c] = (short)hi;
        vll_lds[r][c] = (short)f2bf(v - bf2f(hi));
    }
    wvl_lds[tid] = wvl_w[tid];
    __syncthreads();

    f32x4 C1[4];
#pragma unroll
    for (int nt = 0; nt < 4; nt++) {
        float cb = cen_b[(ntb + nt) * 16 + col];
        C1[nt] = (f32x4){cb, cb, cb, cb};
    }
    {
        const int arow = mt * 16 + col;
#pragma unroll
        for (int ks = 0; ks < 4; ks++) {
            const int k0 = ks * 32 + kg * 8;
            short8 Ah = *(const short8*)&vlh_lds[arow][k0];
            short8 Al = *(const short8*)&vll_lds[arow][k0];
#pragma unroll
            for (int nt = 0; nt < 4; nt++) {
                const int brow = ((ntb + nt) * 16 + col) * 128 + k0;
                short8 Bh = *(const short8*)(cenw_hi + brow);
                short8 Bl = *(const short8*)(cenw_lo + brow);
                C1[nt] = __builtin_amdgcn_mfma_f32_16x16x32_bf16(Ah, Bh, C1[nt], 0, 0, 0);
                C1[nt] = __builtin_amdgcn_mfma_f32_16x16x32_bf16(Al, Bh, C1[nt], 0, 0, 0);
                C1[nt] = __builtin_amdgcn_mfma_f32_16x16x32_bf16(Ah, Bl, C1[nt], 0, 0, 0);
            }
        }
    }

    {
        const int r = tid >> 3;
        const int hh = tid & 7;
        const int og = hh * 16;
        float sseg[16];
#pragma unroll
        for (int q = 0; q < 4; q++) {
            float4 v = *(const float4*)&S_lds[r][og + q * 4];
            sseg[q * 4 + 0] = v.x; sseg[q * 4 + 1] = v.y;
            sseg[q * 4 + 2] = v.z; sseg[q * 4 + 3] = v.w;
        }
        const float flag = (off[n0 + r + 1] > off[n0 + r]) ? 1.f : 0.f;
#pragma unroll
        for (int oo = 0; oo < 16; oo++) {
            float acc = wvl_b[oo] * flag;
            const float* wr = &wvl_lds[oo * 16];
#pragma unroll
            for (int jj = 0; jj < 16; jj++) acc = fmaf(wr[jj], sseg[jj], acc);
            agg_lds[r][og + oo] = acc;
        }
    }
    __syncthreads();

#pragma unroll
    for (int nt = 0; nt < 4; nt++) {
        const int c = (ntb + nt) * 16 + col;
#pragma unroll
        for (int r_ = 0; r_ < 4; r_++) {
            const int rr = mt * 16 + kg * 4 + r_;
            float v = ssp(C1[nt][r_] + agg_lds[rr][c]);
            unsigned short hi = f2bf(v);
            vlh_lds[rr][c] = (short)hi;
            vll_lds[rr][c] = (short)f2bf(v - bf2f(hi));
        }
    }
    __syncthreads();

    f32x4 C2[4];
#pragma unroll
    for (int nt = 0; nt < 4; nt++) {
        float ob = out_b[(ntb + nt) * 16 + col];
        C2[nt] = (f32x4){ob, ob, ob, ob};
    }
    {
        const int arow = mt * 16 + col;
#pragma unroll
        for (int ks = 0; ks < 4; ks++) {
            const int k0 = ks * 32 + kg * 8;
            short8 Ah = *(const short8*)&vlh_lds[arow][k0];
            short8 Al = *(const short8*)&vll_lds[arow][k0];
#pragma unroll
            for (int nt = 0; nt < 4; nt++) {
                const int brow = ((ntb + nt) * 16 + col) * 128 + k0;
                short8 Bh = *(const short8*)(outw_hi + brow);
                short8 Bl = *(const short8*)(outw_lo + brow);
                C2[nt] = __builtin_amdgcn_mfma_f32_16x16x32_bf16(Ah, Bh, C2[nt], 0, 0, 0);
                C2[nt] = __builtin_amdgcn_mfma_f32_16x16x32_bf16(Al, Bh, C2[nt], 0, 0, 0);
                C2[nt] = __builtin_amdgcn_mfma_f32_16x16x32_bf16(Ah, Bl, C2[nt], 0, 0, 0);
            }
        }
    }
#pragma unroll
    for (int nt = 0; nt < 4; nt++) {
        const int c = (ntb + nt) * 16 + col;
#pragma unroll
        for (int r_ = 0; r_ < 4; r_++) {
            S_lds[mt * 16 + kg * 4 + r_][c] = C2[nt][r_];
        }
    }
    __syncthreads();

    {
        const int r = tid >> 3;
        const int g = tid & 7;
        float vals[16];
#pragma unroll
        for (int q = 0; q < 4; q++) {
            float4 v = *(const float4*)&S_lds[r][g * 16 + q * 4];
            vals[q * 4 + 0] = v.x; vals[q * 4 + 1] = v.y;
            vals[q * 4 + 2] = v.z; vals[q * 4 + 3] = v.w;
        }
        float s1 = 0.f, s2 = 0.f;
#pragma unroll
        for (int q = 0; q < 16; q++) { s1 += vals[q]; s2 = fmaf(vals[q], vals[q], s2); }
#pragma unroll
        for (int s = 1; s <= 4; s <<= 1) {
            s1 += __shfl_xor(s1, s);
            s2 += __shfl_xor(s2, s);
        }
        const float mean = s1 * (1.f / 128.f);
        const float var  = s2 * (1.f / 128.f) - mean * mean;
        const float inv  = rsqrtf(var + 1e-5f);
        float o[16];
#pragma unroll
        for (int q = 0; q < 16; q++) {
            const int c = g * 16 + q;
            o[q] = (vals[q] - mean) * inv * ln_g[c] + ln_b[c];
        }
        float* op = out + (size_t)(n0 + r) * 128 + g * 16;
#pragma unroll
        for (int q = 0; q < 4; q++) *(float4*)(op + q * 4) = *(float4*)(o + q * 4);
    }
}

extern "C" void kernel_launch(void* const* d_in, const int* in_sizes, int n_in,
                              void* d_out, int out_size, void* d_ws, size_t ws_size,
                              hipStream_t stream)
{
    (void)in_sizes; (void)n_in; (void)out_size; (void)ws_size;
    const float* node_attr = (const float*)d_in[0];
    const int*   edge_index= (const int*)d_in[1];
    const float* edge_attr = (const float*)d_in[2];
    const float* k_w  = (const float*)d_in[3];
    const float* q_w  = (const float*)d_in[4];
    const float* v_w  = (const float*)d_in[5];
    const float* wk1_w= (const float*)d_in[6];  const float* wk1_b= (const float*)d_in[7];
    const float* wk2_w= (const float*)d_in[8];  const float* wk2_b= (const float*)d_in[9];
    const float* wkl_w= (const float*)d_in[10]; const float* wkl_b= (const float*)d_in[11];
    const float* wv1_w= (const float*)d_in[12]; const float* wv1_b= (const float*)d_in[13];
    const float* wv2_w= (const float*)d_in[14]; const float* wv2_b= (const float*)d_in[15];
    const float* wvl_w= (const float*)d_in[16]; const float* wvl_b= (const float*)d_in[17];
    const float* cen_w= (const float*)d_in[18]; const float* cen_b= (const float*)d_in[19];
    const float* out_w= (const float*)d_in[20]; const float* out_b= (const float*)d_in[21];
    const float* ln_g = (const float*)d_in[22]; const float* ln_b = (const float*)d_in[23];
    float* out = (float*)d_out;

    char* ws = (char*)d_ws;
    size_t o = 0;
    auto alloc = [&](size_t bytes) -> void* {
        void* p = ws + o;
        o += (bytes + 255) & ~(size_t)255;
        return p;
    };
    unsigned int* hkv_g = (unsigned int*)alloc((size_t)NN * 128 * 4);
    float* qt_g  = (float*)alloc((size_t)NN * 128 * 4);
    float* qb_g  = (float*)alloc((size_t)NN * 8 * 4);
    unsigned short* S_g16 = (unsigned short*)alloc((size_t)NN * 128 * 2);
    unsigned int* wkv_csr = (unsigned int*)alloc((size_t)EE * 16 * 4);
    int* cnt     = (int*)alloc((size_t)NN * 4);
    int* off     = (int*)alloc((size_t)(NN + 1) * 4);
    int* cursor  = (int*)alloc((size_t)NN * 4);
    int* csr_e   = (int*)alloc((size_t)EE * 4);
    int* csr_col = (int*)alloc((size_t)EE * 4);
    short* cenw_hi = (short*)alloc(16384 * 2);
    short* cenw_lo = (short*)alloc(16384 * 2);
    short* outw_hi = (short*)alloc(16384 * 2);
    short* outw_lo = (short*)alloc(16384 * 2);
    short* w1k   = (short*)alloc(1024 * 2);
    short* w1v   = (short*)alloc(1024 * 2);
    short* w2k   = (short*)alloc(256 * 2);
    short* w2v   = (short*)alloc(256 * 2);

    hipMemsetAsync(cnt, 0, (size_t)NN * 4, stream);

    prep_w<<<129, 256, 0, stream>>>(cen_w, out_w, wk1_w, wv1_w, wk2_w, wv2_w,
                                    cenw_hi, cenw_lo, outw_hi, outw_lo,
                                    w1k, w1v, w2k, w2v);
    node_pre<<<NN, 128, 0, stream>>>(node_attr, k_w, q_w, v_w, wkl_w, wkl_b,
                                     hkv_g, qt_g, qb_g);
    count_kernel<<<(EE + 255) / 256, 256, 0, stream>>>(edge_index, cnt);
    scan_kernel<<<1, 1024, 0, stream>>>(cnt, off, cursor);
    scatter_kernel<<<(EE + 255) / 256, 256, 0, stream>>>(edge_index, cursor, csr_e, csr_col);
    edge_mlp<<<EE / 64, 256, 0, stream>>>(edge_attr,
                                          w1k, wk1_b, w2k, wk2_b,
                                          w1v, wv1_b, w2v, wv2_b,
                                          csr_e, wkv_csr);
    node_attn<<<NN / 4, 256, 0, stream>>>(off, csr_col, wkv_csr, hkv_g,
                                          qt_g, qb_g, S_g16);
    node_out<<<NN / 32, 256, 0, stream>>>(off, S_g16, node_attr,
                                          cenw_hi, cenw_lo, cen_b,
                                          outw_hi, outw_lo, out_b,
                                          wvl_w, wvl_b, ln_g, ln_b, out);
}

// Round 12
// 276.598 us; speedup vs baseline: 3.3045x; 1.0930x over previous
//
#include <hip/hip_runtime.h>
#include <math.h>

#define NN 20000
#define EE 640000
// H=8, Ch=Kh=16, C=K=128, EC=64

typedef __attribute__((ext_vector_type(8))) short short8;
typedef __attribute__((ext_vector_type(4))) float f32x4;

// PROVEN ssp (R7) — used in node_out epilogue.
__device__ __forceinline__ float ssp(float x) {
    float sp;
    if (x > 20.f)       sp = x;
    else if (x < -20.f) sp = __expf(x);
    else                sp = log1pf(__expf(x));
    return sp - 0.69314718055994530942f;
}

// fast ssp for edge_mlp: hw v_exp+v_log, abs err <= ~3e-7 (vs bf16 noise 4e-3).
// Isolated change vs R11 (green, 302us, absmax 0.078).
__device__ __forceinline__ float ssp_fast(float x) {
    float sp = (x > 15.f) ? x : __logf(1.f + __expf(x));
    return sp - 0.69314718055994530942f;
}

// f2bf: f32 -> bf16 RNE (PROVEN bit-twiddle path)
__device__ __forceinline__ unsigned short f2bf(float f) {
    unsigned u = __float_as_uint(f);
    unsigned r = (u + 0x7FFFu + ((u >> 16) & 1u)) >> 16;
    return (unsigned short)r;
}
__device__ __forceinline__ float bf2f(unsigned short h) {
    return __uint_as_float((unsigned int)h << 16);
}

__device__ __forceinline__ float4 ld4(const float* p) { return *(const float4*)p; }

__device__ __forceinline__ short8 pack8(float4 p, float4 q) {
    short8 r;
    r[0] = (short)f2bf(p.x); r[1] = (short)f2bf(p.y); r[2] = (short)f2bf(p.z); r[3] = (short)f2bf(p.w);
    r[4] = (short)f2bf(q.x); r[5] = (short)f2bf(q.y); r[6] = (short)f2bf(q.z); r[7] = (short)f2bf(q.w);
    return r;
}

// ---------------- one-time weight packing ----------------
__global__ __launch_bounds__(256) void prep_w(
    const float* __restrict__ cen_w, const float* __restrict__ out_w,
    const float* __restrict__ wk1_w, const float* __restrict__ wv1_w,
    const float* __restrict__ wk2_w, const float* __restrict__ wv2_w,
    short* __restrict__ cenw_hi, short* __restrict__ cenw_lo,
    short* __restrict__ outw_hi, short* __restrict__ outw_lo,
    short* __restrict__ w1k, short* __restrict__ w1v,
    short* __restrict__ w2k, short* __restrict__ w2v)
{
    const int b = blockIdx.x, t = threadIdx.x;
    if (b < 64) {
        int idx = b * 256 + t;
        float w = cen_w[idx];
        unsigned short hi = f2bf(w);
        cenw_hi[idx] = (short)hi;
        cenw_lo[idx] = (short)f2bf(w - bf2f(hi));
    } else if (b < 128) {
        int idx = (b - 64) * 256 + t;
        float w = out_w[idx];
        unsigned short hi = f2bf(w);
        outw_hi[idx] = (short)hi;
        outw_lo[idx] = (short)f2bf(w - bf2f(hi));
    } else {
        for (int idx = t; idx < 1024; idx += 256) {
            w1k[idx] = (short)f2bf(wk1_w[idx]);
            w1v[idx] = (short)f2bf(wv1_w[idx]);
        }
        w2k[t] = (short)f2bf(wk2_w[t]);
        w2v[t] = (short)f2bf(wv2_w[t]);
    }
}

// ---------------- per-node precompute (EXACT R7: one node per block) ----------------
// NOTE: 16-nodes/block restructure correlates with absmax 0.067->0.133+ (R8/R9/R10) — banned.
__global__ __launch_bounds__(128) void node_pre(
    const float* __restrict__ node_attr,
    const float* __restrict__ k_w, const float* __restrict__ q_w, const float* __restrict__ v_w,
    const float* __restrict__ wkl_w, const float* __restrict__ wkl_b,
    unsigned int* __restrict__ hkv_g,
    float* __restrict__ qt_g, float* __restrict__ qb_g)
{
    const int n = blockIdx.x;
    const int t = threadIdx.x;
    __shared__ float x[128];
    __shared__ float hq[128];
    x[t] = node_attr[(size_t)n * 128 + t];
    __syncthreads();
    const int h = t >> 4, i = t & 15;
    const float* xh = &x[h * 16];
    const float* kw = &k_w[h * 256 + i * 16];
    const float* qw = &q_w[h * 256 + i * 16];
    const float* vw = &v_w[h * 256 + i * 16];
    float accK = 0.f, accQ = 0.f, accV = 0.f;
#pragma unroll
    for (int j = 0; j < 16; j++) {
        float xv = xh[j];
        accK = fmaf(xv, kw[j], accK);
        accQ = fmaf(xv, qw[j], accQ);
        accV = fmaf(xv, vw[j], accV);
    }
    hkv_g[(size_t)n * 128 + t] = (unsigned int)f2bf(accK) | ((unsigned int)f2bf(accV) << 16);
    hq[t] = accQ;
    __syncthreads();
    float qt = 0.f;
#pragma unroll
    for (int o = 0; o < 16; o++) qt = fmaf(hq[h * 16 + o], wkl_w[o * 16 + i], qt);
    qt_g[(size_t)n * 128 + t] = 0.25f * qt;
    if (i == 0) {
        float qb = 0.f;
#pragma unroll
        for (int o = 0; o < 16; o++) qb = fmaf(hq[h * 16 + o], wkl_b[o], qb);
        qb_g[(size_t)n * 8 + h] = 0.25f * qb;
    }
}

// ---------------- CSR build ----------------
__global__ void count_kernel(const int* __restrict__ ei, int* __restrict__ cnt) {
    int e = blockIdx.x * 256 + threadIdx.x;
    if (e < EE) atomicAdd(&cnt[ei[e]], 1);
}

__global__ __launch_bounds__(1024) void scan_kernel(const int* __restrict__ cnt,
                                                    int* __restrict__ off, int* __restrict__ cursor) {
    __shared__ int arr[1024];
    const int t = threadIdx.x;
    const int STRIP = 20;
    int start = t * STRIP;
    int end = start + STRIP; if (end > NN) end = NN;
    int local = 0;
    for (int n = start; n < end; n++) local += cnt[n];
    arr[t] = local;
    __syncthreads();
    for (int s = 1; s < 1024; s <<= 1) {
        int v = (t >= s) ? arr[t - s] : 0;
        __syncthreads();
        arr[t] += v;
        __syncthreads();
    }
    int running = arr[t] - local;
    for (int n = start; n < end; n++) {
        off[n] = running;
        cursor[n] = running;
        running += cnt[n];
    }
    if (end == NN) off[NN] = running;
}

__global__ void scatter_kernel(const int* __restrict__ ei, int* __restrict__ cursor,
                               int* __restrict__ csr_e, int* __restrict__ csr_col) {
    int e = blockIdx.x * 256 + threadIdx.x;
    if (e < EE) {
        int p = atomicAdd(&cursor[ei[e]], 1);
        csr_e[p] = e;
        csr_col[p] = ei[EE + e];
    }
}

// ---------------- edge MLP pass (MFMA), CSR order ----------------
__global__ __launch_bounds__(256) void edge_mlp(
    const float* __restrict__ edge_attr,
    const short* __restrict__ w1k, const float* __restrict__ wk1_b,
    const short* __restrict__ w2k, const float* __restrict__ wk2_b,
    const short* __restrict__ w1v, const float* __restrict__ wv1_b,
    const short* __restrict__ w2v, const float* __restrict__ wv2_b,
    const int* __restrict__ csr_e,
    unsigned int* __restrict__ wkv_csr)
{
    __shared__ __align__(16) short lds_k[4][16][16];
    __shared__ __align__(16) short lds_v[4][16][16];

    const int t = threadIdx.x;
    const int wid = t >> 6, lane = t & 63;
    const int row = lane & 15;
    const int kg  = lane >> 4;
    const int e0  = blockIdx.x * 64 + wid * 16;

    const int src = csr_e[e0 + row];
    const float* ea = edge_attr + (size_t)src * 64 + kg * 8;
    short8 A0 = pack8(ld4(ea),      ld4(ea + 4));
    short8 A1 = pack8(ld4(ea + 32), ld4(ea + 36));

    short8 BK0 = *(const short8*)(w1k + row * 64 + kg * 8);
    short8 BK1 = *(const short8*)(w1k + row * 64 + kg * 8 + 32);
    short8 BV0 = *(const short8*)(w1v + row * 64 + kg * 8);
    short8 BV1 = *(const short8*)(w1v + row * 64 + kg * 8 + 32);

    float bk = wk1_b[row], bv = wv1_b[row];
    f32x4 ck = {bk, bk, bk, bk};
    f32x4 cv = {bv, bv, bv, bv};
    ck = __builtin_amdgcn_mfma_f32_16x16x32_bf16(A0, BK0, ck, 0, 0, 0);
    ck = __builtin_amdgcn_mfma_f32_16x16x32_bf16(A1, BK1, ck, 0, 0, 0);
    cv = __builtin_amdgcn_mfma_f32_16x16x32_bf16(A0, BV0, cv, 0, 0, 0);
    cv = __builtin_amdgcn_mfma_f32_16x16x32_bf16(A1, BV1, cv, 0, 0, 0);

#pragma unroll
    for (int r = 0; r < 4; r++) {
        lds_k[wid][kg * 4 + r][row] = (short)f2bf(ssp_fast(ck[r]));
        lds_v[wid][kg * 4 + r][row] = (short)f2bf(ssp_fast(cv[r]));
    }
    __syncthreads();

    short8 A2K = (short8)0, A2V = (short8)0, B2K = (short8)0, B2V = (short8)0;
    if (kg < 2) {
        A2K = *(const short8*)&lds_k[wid][row][kg * 8];
        A2V = *(const short8*)&lds_v[wid][row][kg * 8];
        B2K = *(const short8*)(w2k + row * 16 + kg * 8);
        B2V = *(const short8*)(w2v + row * 16 + kg * 8);
    }
    float b2k = wk2_b[row], b2v = wv2_b[row];
    f32x4 c2k = {b2k, b2k, b2k, b2k};
    f32x4 c2v = {b2v, b2v, b2v, b2v};
    c2k = __builtin_amdgcn_mfma_f32_16x16x32_bf16(A2K, B2K, c2k, 0, 0, 0);
    c2v = __builtin_amdgcn_mfma_f32_16x16x32_bf16(A2V, B2V, c2v, 0, 0, 0);

#pragma unroll
    for (int r = 0; r < 4; r++) {
        int el = kg * 4 + r;
        wkv_csr[(size_t)(e0 + el) * 16 + row] =
            (unsigned int)f2bf(c2k[r]) | ((unsigned int)f2bf(c2v[r]) << 16);
    }
}

// ---------------- attention: software-pipelined gathers (bit-identical accumulation) ----------------
__device__ __forceinline__ void edge_step(
    uint4 k0, uint4 k1, uint4 w0, uint4 w1,
    const float* qt, float qbh, bool valid,
    float* U, float& d)
{
    unsigned int kk[8] = {k0.x, k0.y, k0.z, k0.w, k1.x, k1.y, k1.z, k1.w};
    unsigned int ww[8] = {w0.x, w0.y, w0.z, w0.w, w1.x, w1.y, w1.z, w1.w};
    float term = 0.f;
    float uv[8];
#pragma unroll
    for (int i = 0; i < 8; i++) {
        float hk = __uint_as_float(kk[i] << 16);
        float hv = __uint_as_float(kk[i] & 0xFFFF0000u);
        float wk = __uint_as_float(ww[i] << 16);
        float wv = __uint_as_float(ww[i] & 0xFFFF0000u);
        term = fmaf(wk * hk, qt[i], term);
        uv[i] = wv * hv;
    }
    term += __shfl_xor(term, 1);
    float ex = __expf(term + qbh);
    ex = valid ? ex : 0.f;
    d += ex;
#pragma unroll
    for (int i = 0; i < 8; i++) U[i] = fmaf(ex, uv[i], U[i]);
}

#define LOAD_EDGES(J0, KA0,KA1,WA0,WA1,KB0,KB1,WB0,WB1, VA,VB) do {          \
    int jA_ = (J0) + eslot, jB_ = (J0) + 4 + eslot;                          \
    VA = jA_ < end; VB = jB_ < end;                                          \
    int jjA_ = VA ? jA_ : base, jjB_ = VB ? jB_ : base;                      \
    int clA_ = csr_col[jjA_], clB_ = csr_col[jjB_];                          \
    const unsigned int* kpA_ = hkv_g + (size_t)clA_ * 128 + coff;            \
    const unsigned int* wpA_ = wkv_csr + (size_t)jjA_ * 16 + half * 8;       \
    const unsigned int* kpB_ = hkv_g + (size_t)clB_ * 128 + coff;            \
    const unsigned int* wpB_ = wkv_csr + (size_t)jjB_ * 16 + half * 8;       \
    KA0 = *(const uint4*)(kpA_); KA1 = *(const uint4*)(kpA_ + 4);            \
    WA0 = *(const uint4*)(wpA_); WA1 = *(const uint4*)(wpA_ + 4);            \
    KB0 = *(const uint4*)(kpB_); KB1 = *(const uint4*)(kpB_ + 4);            \
    WB0 = *(const uint4*)(wpB_); WB1 = *(const uint4*)(wpB_ + 4);            \
} while (0)

__global__ __launch_bounds__(256) void node_attn(
    const int* __restrict__ off, const int* __restrict__ csr_col,
    const unsigned int* __restrict__ wkv_csr,
    const unsigned int* __restrict__ hkv_g,
    const float* __restrict__ qt_g, const float* __restrict__ qb_g,
    unsigned short* __restrict__ S_g16)
{
    const int wave = threadIdx.x >> 6;
    const int lane = threadIdx.x & 63;
    const int n = blockIdx.x * 4 + wave;
    const int half  = lane & 1;
    const int h     = (lane >> 1) & 7;
    const int eslot = lane >> 4;

    const int base = off[n], end = off[n + 1];
    const int coff = h * 16 + half * 8;

    float qt[8];
    {
        const float* q = qt_g + (size_t)n * 128 + coff;
        *(float4*)(qt + 0) = ld4(q + 0);
        *(float4*)(qt + 4) = ld4(q + 4);
    }
    const float qbh = qb_g[(size_t)n * 8 + h];

    float U[8];
#pragma unroll
    for (int i = 0; i < 8; i++) U[i] = 0.f;
    float d = 0.f;

    if (base < end) {
        uint4 ka0, ka1, wa0, wa1, kb0, kb1, wb0, wb1;
        bool vA, vB;
        LOAD_EDGES(base, ka0, ka1, wa0, wa1, kb0, kb1, wb0, wb1, vA, vB);
        for (int j0 = base; j0 < end; j0 += 8) {
            uint4 nka0, nka1, nwa0, nwa1, nkb0, nkb1, nwb0, nwb1;
            bool nvA = false, nvB = false;
            const int nj = j0 + 8;
            if (nj < end)
                LOAD_EDGES(nj, nka0, nka1, nwa0, nwa1, nkb0, nkb1, nwb0, nwb1, nvA, nvB);
            edge_step(ka0, ka1, wa0, wa1, qt, qbh, vA, U, d);
            edge_step(kb0, kb1, wb0, wb1, qt, qbh, vB, U, d);
            if (nj < end) {
                ka0 = nka0; ka1 = nka1; wa0 = nwa0; wa1 = nwa1;
                kb0 = nkb0; kb1 = nkb1; wb0 = nwb0; wb1 = nwb1;
                vA = nvA; vB = nvB;
            }
        }
    }

#pragma unroll
    for (int s = 16; s <= 32; s <<= 1) {
        d += __shfl_xor(d, s);
#pragma unroll
        for (int i = 0; i < 8; i++) U[i] += __shfl_xor(U[i], s);
    }

    if (lane < 16) {
        const float rd = (end > base) ? (1.f / d) : 0.f;
        short8 o;
#pragma unroll
        for (int i = 0; i < 8; i++) o[i] = (short)f2bf(U[i] * rd);
        *(short8*)(S_g16 + (size_t)n * 128 + coff) = o;
    }
}

// ---------------- epilogue: wvl fold + cen GEMM + ssp + out GEMM + LN ----------------
__global__ __launch_bounds__(256) void node_out(
    const int* __restrict__ off,
    const unsigned short* __restrict__ S_g16,
    const float* __restrict__ node_attr,
    const short* __restrict__ cenw_hi, const short* __restrict__ cenw_lo, const float* __restrict__ cen_b,
    const short* __restrict__ outw_hi, const short* __restrict__ outw_lo, const float* __restrict__ out_b,
    const float* __restrict__ wvl_w, const float* __restrict__ wvl_b,
    const float* __restrict__ ln_g, const float* __restrict__ ln_b,
    float* __restrict__ out)
{
    __shared__ float S_lds[32][132];
    __shared__ float agg_lds[32][132];
    __shared__ __align__(16) short vlh_lds[32][136];
    __shared__ __align__(16) short vll_lds[32][136];
    __shared__ float wvl_lds[256];

    const int tid = threadIdx.x;
    const int w   = tid >> 6;
    const int lane = tid & 63;
    const int col = lane & 15, kg = lane >> 4;
    const int n0 = blockIdx.x * 32;
    const int mt = w & 1;
    const int ntb = (w >> 1) * 4;

    for (int idx = tid; idx < 32 * 128; idx += 256) {
        int r = idx >> 7, c = idx & 127;
        S_lds[r][c] = bf2f(S_g16[(size_t)(n0 + r) * 128 + c]);
        float v = node_attr[(size_t)(n0 + r) * 128 + c];
        unsigned short hi = f2bf(v);
        vlh_lds[r][c] = (short)hi;
        vll_lds[r][c] = (short)f2bf(v - bf2f(hi));
    }
    wvl_lds[tid] = wvl_w[tid];
    __syncthreads();

    f32x4 C1[4];
#pragma unroll
    for (int nt = 0; nt < 4; nt++) {
        float cb = cen_b[(ntb + nt) * 16 + col];
        C1[nt] = (f32x4){cb, cb, cb, cb};
    }
    {
        const int arow = mt * 16 + col;
#pragma unroll
        for (int ks = 0; ks < 4; ks++) {
            const int k0 = ks * 32 + kg * 8;
            short8 Ah = *(const short8*)&vlh_lds[arow][k0];
            short8 Al = *(const short8*)&vll_lds[arow][k0];
#pragma unroll
            for (int nt = 0; nt < 4; nt++) {
                const int brow = ((ntb + nt) * 16 + col) * 128 + k0;
                short8 Bh = *(const short8*)(cenw_hi + brow);
                short8 Bl = *(const short8*)(cenw_lo + brow);
                C1[nt] = __builtin_amdgcn_mfma_f32_16x16x32_bf16(Ah, Bh, C1[nt], 0, 0, 0);
                C1[nt] = __builtin_amdgcn_mfma_f32_16x16x32_bf16(Al, Bh, C1[nt], 0, 0, 0);
                C1[nt] = __builtin_amdgcn_mfma_f32_16x16x32_bf16(Ah, Bl, C1[nt], 0, 0, 0);
            }
        }
    }

    {
        const int r = tid >> 3;
        const int hh = tid & 7;
        const int og = hh * 16;
        float sseg[16];
#pragma unroll
        for (int q = 0; q < 4; q++) {
            float4 v = *(const float4*)&S_lds[r][og + q * 4];
            sseg[q * 4 + 0] = v.x; sseg[q * 4 + 1] = v.y;
            sseg[q * 4 + 2] = v.z; sseg[q * 4 + 3] = v.w;
        }
        const float flag = (off[n0 + r + 1] > off[n0 + r]) ? 1.f : 0.f;
#pragma unroll
        for (int oo = 0; oo < 16; oo++) {
            float acc = wvl_b[oo] * flag;
            const float* wr = &wvl_lds[oo * 16];
#pragma unroll
            for (int jj = 0; jj < 16; jj++) acc = fmaf(wr[jj], sseg[jj], acc);
            agg_lds[r][og + oo] = acc;
        }
    }
    __syncthreads();

#pragma unroll
    for (int nt = 0; nt < 4; nt++) {
        const int c = (ntb + nt) * 16 + col;
#pragma unroll
        for (int r_ = 0; r_ < 4; r_++) {
            const int rr = mt * 16 + kg * 4 + r_;
            float v = ssp(C1[nt][r_] + agg_lds[rr][c]);
            unsigned short hi = f2bf(v);
            vlh_lds[rr][c] = (short)hi;
            vll_lds[rr][c] = (short)f2bf(v - bf2f(hi));
        }
    }
    __syncthreads();

    f32x4 C2[4];
#pragma unroll
    for (int nt = 0; nt < 4; nt++) {
        float ob = out_b[(ntb + nt) * 16 + col];
        C2[nt] = (f32x4){ob, ob, ob, ob};
    }
    {
        const int arow = mt * 16 + col;
#pragma unroll
        for (int ks = 0; ks < 4; ks++) {
            const int k0 = ks * 32 + kg * 8;
            short8 Ah = *(const short8*)&vlh_lds[arow][k0];
            short8 Al = *(const short8*)&vll_lds[arow][k0];
#pragma unroll
            for (int nt = 0; nt < 4; nt++) {
                const int brow = ((ntb + nt) * 16 + col) * 128 + k0;
                short8 Bh = *(const short8*)(outw_hi + brow);
                short8 Bl = *(const short8*)(outw_lo + brow);
                C2[nt] = __builtin_amdgcn_mfma_f32_16x16x32_bf16(Ah, Bh, C2[nt], 0, 0, 0);
                C2[nt] = __builtin_amdgcn_mfma_f32_16x16x32_bf16(Al, Bh, C2[nt], 0, 0, 0);
                C2[nt] = __builtin_amdgcn_mfma_f32_16x16x32_bf16(Ah, Bl, C2[nt], 0, 0, 0);
            }
        }
    }
#pragma unroll
    for (int nt = 0; nt < 4; nt++) {
        const int c = (ntb + nt) * 16 + col;
#pragma unroll
        for (int r_ = 0; r_ < 4; r_++) {
            S_lds[mt * 16 + kg * 4 + r_][c] = C2[nt][r_];
        }
    }
    __syncthreads();

    {
        const int r = tid >> 3;
        const int g = tid & 7;
        float vals[16];
#pragma unroll
        for (int q = 0; q < 4; q++) {
            float4 v = *(const float4*)&S_lds[r][g * 16 + q * 4];
            vals[q * 4 + 0] = v.x; vals[q * 4 + 1] = v.y;
            vals[q * 4 + 2] = v.z; vals[q * 4 + 3] = v.w;
        }
        float s1 = 0.f, s2 = 0.f;
#pragma unroll
        for (int q = 0; q < 16; q++) { s1 += vals[q]; s2 = fmaf(vals[q], vals[q], s2); }
#pragma unroll
        for (int s = 1; s <= 4; s <<= 1) {
            s1 += __shfl_xor(s1, s);
            s2 += __shfl_xor(s2, s);
        }
        const float mean = s1 * (1.f / 128.f);
        const float var  = s2 * (1.f / 128.f) - mean * mean;
        const float inv  = rsqrtf(var + 1e-5f);
        float o[16];
#pragma unroll
        for (int q = 0; q < 16; q++) {
            const int c = g * 16 + q;
            o[q] = (vals[q] - mean) * inv * ln_g[c] + ln_b[c];
        }
        float* op = out + (size_t)(n0 + r) * 128 + g * 16;
#pragma unroll
        for (int q = 0; q < 4; q++) *(float4*)(op + q * 4) = *(float4*)(o + q * 4);
    }
}

extern "C" void kernel_launch(void* const* d_in, const int* in_sizes, int n_in,
                              void* d_out, int out_size, void* d_ws, size_t ws_size,
                              hipStream_t stream)
{
    (void)in_sizes; (void)n_in; (void)out_size; (void)ws_size;
    const float* node_attr = (const float*)d_in[0];
    const int*   edge_index= (const int*)d_in[1];
    const float* edge_attr = (const float*)d_in[2];
    const float* k_w  = (const float*)d_in[3];
    const float* q_w  = (const float*)d_in[4];
    const float* v_w  = (const float*)d_in[5];
    const float* wk1_w= (const float*)d_in[6];  const float* wk1_b= (const float*)d_in[7];
    const float* wk2_w= (const float*)d_in[8];  const float* wk2_b= (const float*)d_in[9];
    const float* wkl_w= (const float*)d_in[10]; const float* wkl_b= (const float*)d_in[11];
    const float* wv1_w= (const float*)d_in[12]; const float* wv1_b= (const float*)d_in[13];
    const float* wv2_w= (const float*)d_in[14]; const float* wv2_b= (const float*)d_in[15];
    const float* wvl_w= (const float*)d_in[16]; const float* wvl_b= (const float*)d_in[17];
    const float* cen_w= (const float*)d_in[18]; const float* cen_b= (const float*)d_in[19];
    const float* out_w= (const float*)d_in[20]; const float* out_b= (const float*)d_in[21];
    const float* ln_g = (const float*)d_in[22]; const float* ln_b = (const float*)d_in[23];
    float* out = (float*)d_out;

    char* ws = (char*)d_ws;
    size_t o = 0;
    auto alloc = [&](size_t bytes) -> void* {
        void* p = ws + o;
        o += (bytes + 255) & ~(size_t)255;
        return p;
    };
    unsigned int* hkv_g = (unsigned int*)alloc((size_t)NN * 128 * 4);
    float* qt_g  = (float*)alloc((size_t)NN * 128 * 4);
    float* qb_g  = (float*)alloc((size_t)NN * 8 * 4);
    unsigned short* S_g16 = (unsigned short*)alloc((size_t)NN * 128 * 2);
    unsigned int* wkv_csr = (unsigned int*)alloc((size_t)EE * 16 * 4);
    int* cnt     = (int*)alloc((size_t)NN * 4);
    int* off     = (int*)alloc((size_t)(NN + 1) * 4);
    int* cursor  = (int*)alloc((size_t)NN * 4);
    int* csr_e   = (int*)alloc((size_t)EE * 4);
    int* csr_col = (int*)alloc((size_t)EE * 4);
    short* cenw_hi = (short*)alloc(16384 * 2);
    short* cenw_lo = (short*)alloc(16384 * 2);
    short* outw_hi = (short*)alloc(16384 * 2);
    short* outw_lo = (short*)alloc(16384 * 2);
    short* w1k   = (short*)alloc(1024 * 2);
    short* w1v   = (short*)alloc(1024 * 2);
    short* w2k   = (short*)alloc(256 * 2);
    short* w2v   = (short*)alloc(256 * 2);

    hipMemsetAsync(cnt, 0, (size_t)NN * 4, stream);

    prep_w<<<129, 256, 0, stream>>>(cen_w, out_w, wk1_w, wv1_w, wk2_w, wv2_w,
                                    cenw_hi, cenw_lo, outw_hi, outw_lo,
                                    w1k, w1v, w2k, w2v);
    node_pre<<<NN, 128, 0, stream>>>(node_attr, k_w, q_w, v_w, wkl_w, wkl_b,
                                     hkv_g, qt_g, qb_g);
    count_kernel<<<(EE + 255) / 256, 256, 0, stream>>>(edge_index, cnt);
    scan_kernel<<<1, 1024, 0, stream>>>(cnt, off, cursor);
    scatter_kernel<<<(EE + 255) / 256, 256, 0, stream>>>(edge_index, cursor, csr_e, csr_col);
    edge_mlp<<<EE / 64, 256, 0, stream>>>(edge_attr,
                                          w1k, wk1_b, w2k, wk2_b,
                                          w1v, wv1_b, w2v, wv2_b,
                                          csr_e, wkv_csr);
    node_attn<<<NN / 4, 256, 0, stream>>>(off, csr_col, wkv_csr, hkv_g,
                                          qt_g, qb_g, S_g16);
    node_out<<<NN / 32, 256, 0, stream>>>(off, S_g16, node_attr,
                                          cenw_hi, cenw_lo, cen_b,
                                          outw_hi, outw_lo, out_b,
                                          wvl_w, wvl_b, ln_g, ln_b, out);
}